// Round 4
// baseline (1428.094 us; speedup 1.0000x reference)
//
#include <hip/hip_runtime.h>
#include <hip/hip_bf16.h>
#include <stdint.h>

#define TT 1024
#define EE 1024
#define HH 16
#define DD 64
#define BHN 32
#define HB 153
#define RECW 102
#define RING 8
#define NEGF (-3.4028234663852886e38f)

typedef unsigned long long ull;

// workspace layout (float element offsets)
#define OFF_Q  ((size_t)0)
#define OFF_K  (OFF_Q + (size_t)BHN*TT*DD)
#define OFF_V  (OFF_K + (size_t)BHN*TT*DD)
#define OFF_AW (OFF_V + (size_t)BHN*TT*DD)
#define OFF_M  (OFF_AW + (size_t)BHN*TT*TT)
#define OFF_S  (OFF_M + (size_t)BHN*TT)
#define OFF_AO (OFF_S + (size_t)BHN*TT)
#define OFF_END (OFF_AO + (size_t)BHN*TT*DD)
// after OFF_END: initacc float[BHN*256], evict int[BHN*1024]

// ---------------- GEMM: Y = X @ W + b (optionally scaled, optionally head-split store)
__global__ __launch_bounds__(256) void k_proj(const float* __restrict__ X,
    const float* __restrict__ W, const float* __restrict__ bias,
    float* __restrict__ Y, float scale, int headsplit) {
  __shared__ float As[64][17];
  __shared__ float Bs[16][65];
  int tid = threadIdx.x;
  int tx = tid & 15, ty = tid >> 4;
  int r0 = blockIdx.y * 64, c0 = blockIdx.x * 64;
  float acc[4][4] = {};
  for (int k0 = 0; k0 < EE; k0 += 16) {
    {
      int i = tid >> 2;
      int kk = (tid & 3) * 4;
      const float4 a = *(const float4*)&X[(size_t)(r0 + i) * EE + k0 + kk];
      As[i][kk] = a.x; As[i][kk+1] = a.y; As[i][kk+2] = a.z; As[i][kk+3] = a.w;
    }
    {
      int kk = tid >> 4;
      int j = (tid & 15) * 4;
      const float4 b = *(const float4*)&W[(size_t)(k0 + kk) * EE + c0 + j];
      Bs[kk][j] = b.x; Bs[kk][j+1] = b.y; Bs[kk][j+2] = b.z; Bs[kk][j+3] = b.w;
    }
    __syncthreads();
    #pragma unroll
    for (int kk = 0; kk < 16; ++kk) {
      float a[4], b[4];
      #pragma unroll
      for (int u = 0; u < 4; ++u) a[u] = As[ty*4+u][kk];
      #pragma unroll
      for (int v = 0; v < 4; ++v) b[v] = Bs[kk][tx*4+v];
      #pragma unroll
      for (int u = 0; u < 4; ++u)
        #pragma unroll
        for (int v = 0; v < 4; ++v) acc[u][v] += a[u]*b[v];
    }
    __syncthreads();
  }
  #pragma unroll
  for (int u = 0; u < 4; ++u) {
    int r = r0 + ty*4 + u;
    #pragma unroll
    for (int v = 0; v < 4; ++v) {
      int c = c0 + tx*4 + v;
      float val = (acc[u][v] + bias[c]) * scale;
      if (headsplit) {
        int b_ = r >> 10, t_ = r & 1023, h_ = c >> 6, d_ = c & 63;
        Y[(((size_t)(b_*HH + h_) * TT) + t_) * DD + d_] = val;
      } else {
        Y[(size_t)r * EE + c] = val;
      }
    }
  }
}

// ---------------- batched QK^T
__global__ __launch_bounds__(256) void k_qk(const float* __restrict__ q,
    const float* __restrict__ k, float* __restrict__ aw) {
  int bh = blockIdx.z;
  int t0 = blockIdx.y * 64, s0 = blockIdx.x * 64;
  if (s0 > t0 + 63) return;
  __shared__ float Qs[64][65];
  __shared__ float Ks[64][65];
  int tid = threadIdx.x;
  const float* qb = q + (size_t)bh * TT * DD;
  const float* kb = k + (size_t)bh * TT * DD;
  #pragma unroll
  for (int u = 0; u < 4; ++u) {
    int fi = tid + u * 256;
    int row = fi >> 4, c4 = (fi & 15) * 4;
    float4 a = *(const float4*)&qb[(size_t)(t0 + row) * DD + c4];
    Qs[row][c4] = a.x; Qs[row][c4+1] = a.y; Qs[row][c4+2] = a.z; Qs[row][c4+3] = a.w;
    float4 b = *(const float4*)&kb[(size_t)(s0 + row) * DD + c4];
    Ks[row][c4] = b.x; Ks[row][c4+1] = b.y; Ks[row][c4+2] = b.z; Ks[row][c4+3] = b.w;
  }
  __syncthreads();
  int tx = tid & 15, ty = tid >> 4;
  float acc[4][4] = {};
  #pragma unroll 8
  for (int kk = 0; kk < 64; ++kk) {
    float a[4], b[4];
    #pragma unroll
    for (int u = 0; u < 4; ++u) a[u] = Qs[ty*4+u][kk];
    #pragma unroll
    for (int v = 0; v < 4; ++v) b[v] = Ks[tx*4+v][kk];
    #pragma unroll
    for (int u = 0; u < 4; ++u)
      #pragma unroll
      for (int v = 0; v < 4; ++v) acc[u][v] += a[u]*b[v];
  }
  float* awb = aw + (size_t)bh * TT * TT;
  #pragma unroll
  for (int u = 0; u < 4; ++u) {
    int t_ = t0 + ty*4 + u;
    #pragma unroll
    for (int v = 0; v < 4; ++v)
      awb[(size_t)t_ * TT + s0 + tx*4 + v] = acc[u][v];
  }
}

// ---------------- row softmax in place: aw row -> probs (lower triangle only)
__global__ __launch_bounds__(256) void k_softmax(float* __restrict__ aw) {
  int bh = blockIdx.y;
  int wid = threadIdx.x >> 6, lane = threadIdx.x & 63;
  int t = blockIdx.x * 4 + wid;
  float* row = aw + ((size_t)bh * TT + t) * TT;
  float vals[16];
  float m = NEGF;
  #pragma unroll
  for (int i = 0; i < 16; ++i) {
    int j = lane + 64*i;
    vals[i] = (j <= t) ? row[j] : NEGF;
    m = fmaxf(m, vals[i]);
  }
  for (int o = 32; o; o >>= 1) m = fmaxf(m, __shfl_xor(m, o));
  float s = 0.f;
  #pragma unroll
  for (int i = 0; i < 16; ++i) {
    int j = lane + 64*i;
    if (j <= t) { vals[i] = expf(vals[i] - m); s += vals[i]; }
  }
  for (int o = 32; o; o >>= 1) s += __shfl_xor(s, o);
  float inv = 1.0f / s;
  #pragma unroll
  for (int i = 0; i < 16; ++i) {
    int j = lane + 64*i;
    if (j <= t) row[j] = vals[i] * inv;
  }
}

// ---------------- parallel init of heavy-hitter scores (p = probs)
__global__ __launch_bounds__(256) void k_init_acc(const float* __restrict__ p,
    float* __restrict__ initacc) {
  int bh = blockIdx.x;
  int c = threadIdx.x;
  float val = 0.f;
  if (c < HB) {
    const float* pb = p + (size_t)bh * TT * TT;
    for (int i = c; i < HB; ++i)
      val += pb[(size_t)i * TT + c];
  }
  initacc[(size_t)bh * 256 + c] = val;
}

// ---------------- wave-wide min over u32 via DPP (VALU path, no LDS)
#define DPP_HOP(ctrl)                                                        \
  {                                                                          \
    unsigned tt = (unsigned)__builtin_amdgcn_update_dpp(                     \
        (int)0xFFFFFFFFu, (int)x, (ctrl), 0xF, 0xF, false);                  \
    x = x < tt ? x : tt;                                                     \
  }
__device__ __forceinline__ unsigned wave_min_u32(unsigned x) {
  DPP_HOP(0x111)  // row_shr:1
  DPP_HOP(0x112)  // row_shr:2
  DPP_HOP(0x114)  // row_shr:4
  DPP_HOP(0x118)  // row_shr:8
  DPP_HOP(0x142)  // row_bcast:15
  DPP_HOP(0x143)  // row_bcast:31
  return (unsigned)__builtin_amdgcn_readlane((int)x, 63);
}

// ---------------- serial heavy-hitter scan: producer wave + consumer wave
__global__ __launch_bounds__(128) void k_scan(const float* __restrict__ p,
    const float* __restrict__ initacc, int* __restrict__ evict_g) {
  int bh = blockIdx.x;
  int tid = threadIdx.x;
  int lane = tid & 63;
  const float* pb = p + (size_t)bh * TT * TT;
  __shared__ float ring[RING][TT];
  __shared__ int ev[TT];
  __shared__ volatile int rdyf[RING];
  __shared__ volatile int donef;
  for (int i = tid; i < TT; i += 128) ev[i] = 0x7fffffff;
  if (tid < RING) rdyf[tid] = -1;
  if (tid == 0) donef = -1;
  __syncthreads();

  if (tid >= 64) {
    // ---------- producer: stream prob rows HB..TT-1 into the ring ----------
    float4 R[4][4];
    #pragma unroll
    for (int i = 0; i < 4; ++i) {
      const float4* src = (const float4*)(pb + (size_t)(HB + i) * TT);
      #pragma unroll
      for (int j = 0; j < 4; ++j) R[i][j] = src[lane + 64*j];
    }
    for (int t = HB; t < TT; ++t) {
      int k = (t - HB) & 3;
      int slot = t & (RING - 1);
      if (t >= HB + RING) {
        while (donef < t - RING) { __builtin_amdgcn_s_sleep(1); }
      }
      float4* dst = (float4*)ring[slot];
      #pragma unroll
      for (int j = 0; j < 4; ++j) dst[lane + 64*j] = R[k][j];
      asm volatile("s_waitcnt lgkmcnt(0)" ::: "memory");
      if (lane == 0) rdyf[slot] = t;
      if (t + 4 < TT) {
        const float4* src = (const float4*)(pb + (size_t)(t + 4) * TT);
        #pragma unroll
        for (int j = 0; j < 4; ++j) R[k][j] = src[lane + 64*j];
      }
    }
  } else {
    // ---------- consumer: serial scan, LDS-only critical path ----------
    bool act2 = lane < (HB - 128);   // lane < 25
    int col[3]; float sc[3];
    col[0] = lane;
    col[1] = 64 + lane;
    col[2] = act2 ? (128 + lane) : 0;
    sc[0] = initacc[(size_t)bh * 256 + lane];
    sc[1] = initacc[(size_t)bh * 256 + 64 + lane];
    sc[2] = act2 ? initacc[(size_t)bh * 256 + 128 + lane] : 0.f;
    int fpeek = -2;
    for (int t = HB; t < TT; ++t) {
      int slot = t & (RING - 1);
      if (fpeek != t) {
        while (rdyf[slot] != t) { __builtin_amdgcn_s_sleep(1); }
      }
      asm volatile("" ::: "memory");
      const float* rb = ring[slot];
      float r0 = rb[col[0]];
      float r1 = rb[col[1]];
      float r2 = rb[col[2]];
      float rd = rb[t];                       // diagonal prob p[t][t]
      fpeek = rdyf[(t + 1) & (RING - 1)];     // early peek for next step
      // keys from pre-update scores; min score evicted, tie -> larger col
      unsigned b0 = __float_as_uint(sc[0]);
      unsigned b1 = __float_as_uint(sc[1]);
      unsigned b2 = act2 ? __float_as_uint(sc[2]) : 0xFFFFFFFFu;
      unsigned mn = b0 < b1 ? b0 : b1; mn = mn < b2 ? mn : b2;
      unsigned mstar = wave_min_u32(mn);
      unsigned c0k = (b0 == mstar) ? (unsigned)(1023 - col[0]) : 0xFFFFFFFFu;
      unsigned c1k = (b1 == mstar) ? (unsigned)(1023 - col[1]) : 0xFFFFFFFFu;
      unsigned c2k = (act2 && b2 == mstar) ? (unsigned)(1023 - col[2]) : 0xFFFFFFFFu;
      unsigned cm = c0k < c1k ? c0k : c1k; cm = cm < c2k ? cm : c2k;
      int cstar = 1023 - (int)wave_min_u32(cm);
      if (b0 == mstar && col[0] == cstar) { ev[col[0]] = t; col[0] = t; sc[0] = rd; }
      else sc[0] += r0;
      if (b1 == mstar && col[1] == cstar) { ev[col[1]] = t; col[1] = t; sc[1] = rd; }
      else sc[1] += r1;
      if (act2) {
        if (b2 == mstar && col[2] == cstar) { ev[col[2]] = t; col[2] = t; sc[2] = rd; }
        else sc[2] += r2;
      }
      asm volatile("" ::: "memory");
      if (lane == 0 && (t & 3) == 3) donef = t;
    }
  }

  __syncthreads();
  int4* dst4 = (int4*)(evict_g + (size_t)bh * TT);
  const int4* src4 = (const int4*)ev;
  for (int i = tid; i < TT/4; i += 128) dst4[i] = src4[i];
}

// ---------------- masked renormalize + PV (p = probs)
__global__ __launch_bounds__(256) void k_attn(const float* __restrict__ p,
    const int* __restrict__ evict_g,
    const float* __restrict__ v, float* __restrict__ ao) {
  int bh = blockIdx.y, t = blockIdx.x;
  int tid = threadIdx.x;
  const float* row = p + ((size_t)bh * TT + t) * TT;
  __shared__ float pr[TT];
  __shared__ float red[4];
  __shared__ float pv[4][64];
  __shared__ int et[TT];
  ((int4*)et)[tid] = ((const int4*)(evict_g + (size_t)bh * TT))[tid];
  __syncthreads();

  float e[4];
  float s = 0.f;
  #pragma unroll
  for (int i = 0; i < 4; ++i) {
    int j = tid + 256*i;
    bool allow = (j <= t) && ((et[j] > t) || (j + RECW >= t));
    e[i] = allow ? row[j] : 0.f;
    s += e[i];
  }
  for (int o = 32; o; o >>= 1) s += __shfl_xor(s, o);
  int wid = tid >> 6;
  if ((tid & 63) == 0) red[wid] = s;
  __syncthreads();
  s = red[0] + red[1] + red[2] + red[3];
  float inv = 1.f / s;
  #pragma unroll
  for (int i = 0; i < 4; ++i) pr[tid + 256*i] = e[i] * inv;
  __syncthreads();

  int g = tid >> 6, d = tid & 63;
  const float* vb = v + (size_t)bh * TT * DD;
  float acc = 0.f;
  int lim = t + 1 - g*256; if (lim > 256) lim = 256;
  for (int i = 0; i < lim; ++i) {
    int j = g * 256 + i;
    acc += pr[j] * vb[(size_t)j * DD + d];
  }
  pv[g][d] = acc;
  __syncthreads();
  if (tid < 64) {
    float r = pv[0][tid] + pv[1][tid] + pv[2][tid] + pv[3][tid];
    int b_ = bh >> 4, h_ = bh & 15;
    ao[((size_t)b_ * TT + t) * EE + h_ * DD + tid] = r;
  }
}

extern "C" void kernel_launch(void* const* d_in, const int* in_sizes, int n_in,
                              void* d_out, int out_size, void* d_ws, size_t ws_size,
                              hipStream_t stream) {
  const float* hs = (const float*)d_in[0];
  const float* Wq = (const float*)d_in[2];
  const float* bq = (const float*)d_in[3];
  const float* Wk = (const float*)d_in[4];
  const float* bk = (const float*)d_in[5];
  const float* Wv = (const float*)d_in[6];
  const float* bv = (const float*)d_in[7];
  const float* Wo = (const float*)d_in[8];
  const float* bo = (const float*)d_in[9];
  float* out = (float*)d_out;

  float* ws = (float*)d_ws;
  float* q  = ws + OFF_Q;
  float* k  = ws + OFF_K;
  float* v  = ws + OFF_V;
  float* aw = ws + OFF_AW;   // becomes probs after k_softmax
  float* ao = ws + OFF_AO;
  float* initacc = ws + OFF_END;
  int* evict = (int*)(ws + OFF_END + (size_t)BHN * 256);

  dim3 gproj(16, 32);
  k_proj<<<gproj, 256, 0, stream>>>(hs, Wq, bq, q, 0.125f, 1);
  k_proj<<<gproj, 256, 0, stream>>>(hs, Wk, bk, k, 1.0f, 1);
  k_proj<<<gproj, 256, 0, stream>>>(hs, Wv, bv, v, 1.0f, 1);

  dim3 gqk(16, 16, BHN);
  k_qk<<<gqk, 256, 0, stream>>>(q, k, aw);

  dim3 grs(TT/4, BHN);
  k_softmax<<<grs, 256, 0, stream>>>(aw);

  k_init_acc<<<BHN, 256, 0, stream>>>(aw, initacc);

  k_scan<<<BHN, 128, 0, stream>>>(aw, initacc, evict);

  dim3 gat(TT, BHN);
  k_attn<<<gat, 256, 0, stream>>>(aw, evict, v, ao);

  k_proj<<<gproj, 256, 0, stream>>>(ao, Wo, bo, out, 1.0f, 0);
}

// Round 5
// 1404.569 us; speedup vs baseline: 1.0167x; 1.0167x over previous
//
#include <hip/hip_runtime.h>
#include <hip/hip_bf16.h>
#include <stdint.h>

#define TT 1024
#define EE 1024
#define HH 16
#define DD 64
#define BHN 32
#define HB 153
#define RECW 102
#define RING 8
#define NEGF (-3.4028234663852886e38f)

typedef unsigned long long ull;

// workspace layout (float element offsets)
#define OFF_Q  ((size_t)0)
#define OFF_K  (OFF_Q + (size_t)BHN*TT*DD)
#define OFF_V  (OFF_K + (size_t)BHN*TT*DD)
#define OFF_AW (OFF_V + (size_t)BHN*TT*DD)
#define OFF_M  (OFF_AW + (size_t)BHN*TT*TT)
#define OFF_S  (OFF_M + (size_t)BHN*TT)
#define OFF_AO (OFF_S + (size_t)BHN*TT)
#define OFF_END (OFF_AO + (size_t)BHN*TT*DD)
// after OFF_END: initacc float[BHN*256], evict int[BHN*1024]

// ---------------- GEMM: Y = X @ W + b (optionally scaled, optionally head-split store)
__global__ __launch_bounds__(256) void k_proj(const float* __restrict__ X,
    const float* __restrict__ W, const float* __restrict__ bias,
    float* __restrict__ Y, float scale, int headsplit) {
  __shared__ float As[64][17];
  __shared__ float Bs[16][65];
  int tid = threadIdx.x;
  int tx = tid & 15, ty = tid >> 4;
  int r0 = blockIdx.y * 64, c0 = blockIdx.x * 64;
  float acc[4][4] = {};
  for (int k0 = 0; k0 < EE; k0 += 16) {
    {
      int i = tid >> 2;
      int kk = (tid & 3) * 4;
      const float4 a = *(const float4*)&X[(size_t)(r0 + i) * EE + k0 + kk];
      As[i][kk] = a.x; As[i][kk+1] = a.y; As[i][kk+2] = a.z; As[i][kk+3] = a.w;
    }
    {
      int kk = tid >> 4;
      int j = (tid & 15) * 4;
      const float4 b = *(const float4*)&W[(size_t)(k0 + kk) * EE + c0 + j];
      Bs[kk][j] = b.x; Bs[kk][j+1] = b.y; Bs[kk][j+2] = b.z; Bs[kk][j+3] = b.w;
    }
    __syncthreads();
    #pragma unroll
    for (int kk = 0; kk < 16; ++kk) {
      float a[4], b[4];
      #pragma unroll
      for (int u = 0; u < 4; ++u) a[u] = As[ty*4+u][kk];
      #pragma unroll
      for (int v = 0; v < 4; ++v) b[v] = Bs[kk][tx*4+v];
      #pragma unroll
      for (int u = 0; u < 4; ++u)
        #pragma unroll
        for (int v = 0; v < 4; ++v) acc[u][v] += a[u]*b[v];
    }
    __syncthreads();
  }
  #pragma unroll
  for (int u = 0; u < 4; ++u) {
    int r = r0 + ty*4 + u;
    #pragma unroll
    for (int v = 0; v < 4; ++v) {
      int c = c0 + tx*4 + v;
      float val = (acc[u][v] + bias[c]) * scale;
      if (headsplit) {
        int b_ = r >> 10, t_ = r & 1023, h_ = c >> 6, d_ = c & 63;
        Y[(((size_t)(b_*HH + h_) * TT) + t_) * DD + d_] = val;
      } else {
        Y[(size_t)r * EE + c] = val;
      }
    }
  }
}

// ---------------- batched QK^T
__global__ __launch_bounds__(256) void k_qk(const float* __restrict__ q,
    const float* __restrict__ k, float* __restrict__ aw) {
  int bh = blockIdx.z;
  int t0 = blockIdx.y * 64, s0 = blockIdx.x * 64;
  if (s0 > t0 + 63) return;
  __shared__ float Qs[64][65];
  __shared__ float Ks[64][65];
  int tid = threadIdx.x;
  const float* qb = q + (size_t)bh * TT * DD;
  const float* kb = k + (size_t)bh * TT * DD;
  #pragma unroll
  for (int u = 0; u < 4; ++u) {
    int fi = tid + u * 256;
    int row = fi >> 4, c4 = (fi & 15) * 4;
    float4 a = *(const float4*)&qb[(size_t)(t0 + row) * DD + c4];
    Qs[row][c4] = a.x; Qs[row][c4+1] = a.y; Qs[row][c4+2] = a.z; Qs[row][c4+3] = a.w;
    float4 b = *(const float4*)&kb[(size_t)(s0 + row) * DD + c4];
    Ks[row][c4] = b.x; Ks[row][c4+1] = b.y; Ks[row][c4+2] = b.z; Ks[row][c4+3] = b.w;
  }
  __syncthreads();
  int tx = tid & 15, ty = tid >> 4;
  float acc[4][4] = {};
  #pragma unroll 8
  for (int kk = 0; kk < 64; ++kk) {
    float a[4], b[4];
    #pragma unroll
    for (int u = 0; u < 4; ++u) a[u] = Qs[ty*4+u][kk];
    #pragma unroll
    for (int v = 0; v < 4; ++v) b[v] = Ks[tx*4+v][kk];
    #pragma unroll
    for (int u = 0; u < 4; ++u)
      #pragma unroll
      for (int v = 0; v < 4; ++v) acc[u][v] += a[u]*b[v];
  }
  float* awb = aw + (size_t)bh * TT * TT;
  #pragma unroll
  for (int u = 0; u < 4; ++u) {
    int t_ = t0 + ty*4 + u;
    #pragma unroll
    for (int v = 0; v < 4; ++v)
      awb[(size_t)t_ * TT + s0 + tx*4 + v] = acc[u][v];
  }
}

// ---------------- row softmax in place: aw row -> probs (lower triangle only)
__global__ __launch_bounds__(256) void k_softmax(float* __restrict__ aw) {
  int bh = blockIdx.y;
  int wid = threadIdx.x >> 6, lane = threadIdx.x & 63;
  int t = blockIdx.x * 4 + wid;
  float* row = aw + ((size_t)bh * TT + t) * TT;
  float vals[16];
  float m = NEGF;
  #pragma unroll
  for (int i = 0; i < 16; ++i) {
    int j = lane + 64*i;
    vals[i] = (j <= t) ? row[j] : NEGF;
    m = fmaxf(m, vals[i]);
  }
  for (int o = 32; o; o >>= 1) m = fmaxf(m, __shfl_xor(m, o));
  float s = 0.f;
  #pragma unroll
  for (int i = 0; i < 16; ++i) {
    int j = lane + 64*i;
    if (j <= t) { vals[i] = expf(vals[i] - m); s += vals[i]; }
  }
  for (int o = 32; o; o >>= 1) s += __shfl_xor(s, o);
  float inv = 1.0f / s;
  #pragma unroll
  for (int i = 0; i < 16; ++i) {
    int j = lane + 64*i;
    if (j <= t) row[j] = vals[i] * inv;
  }
}

// ---------------- parallel init of heavy-hitter scores (p = probs)
__global__ __launch_bounds__(256) void k_init_acc(const float* __restrict__ p,
    float* __restrict__ initacc) {
  int bh = blockIdx.x;
  int c = threadIdx.x;
  float val = 0.f;
  if (c < HB) {
    const float* pb = p + (size_t)bh * TT * TT;
    for (int i = c; i < HB; ++i)
      val += pb[(size_t)i * TT + c];
  }
  initacc[(size_t)bh * 256 + c] = val;
}

// ---------------- wave-wide min over u32 via DPP (VALU path, no LDS)
#define DPP_HOP(ctrl)                                                        \
  {                                                                          \
    unsigned tt = (unsigned)__builtin_amdgcn_update_dpp(                     \
        (int)0xFFFFFFFFu, (int)x, (ctrl), 0xF, 0xF, false);                  \
    x = x < tt ? x : tt;                                                     \
  }
__device__ __forceinline__ unsigned wave_min_u32(unsigned x) {
  DPP_HOP(0x111)  // row_shr:1
  DPP_HOP(0x112)  // row_shr:2
  DPP_HOP(0x114)  // row_shr:4
  DPP_HOP(0x118)  // row_shr:8
  DPP_HOP(0x142)  // row_bcast:15
  DPP_HOP(0x143)  // row_bcast:31
  return (unsigned)__builtin_amdgcn_readlane((int)x, 63);
}

// producer step: write bank BK (4 float4, statically indexed) to ring slot,
// publish flag, then refill BK from row (t)+4. All literal indices -> VGPRs.
#define PROD_STEP(BK, t_)                                                     \
  do {                                                                        \
    if ((t_) >= HB + RING) {                                                  \
      while (donef < (t_) - RING) { __builtin_amdgcn_s_sleep(1); }            \
    }                                                                         \
    float4* dst_ = (float4*)ring[(t_) & (RING - 1)];                          \
    dst_[lane]       = BK[0];                                                 \
    dst_[lane + 64]  = BK[1];                                                 \
    dst_[lane + 128] = BK[2];                                                 \
    dst_[lane + 192] = BK[3];                                                 \
    asm volatile("s_waitcnt lgkmcnt(0)" ::: "memory");                        \
    if (lane == 0) rdyf[(t_) & (RING - 1)] = (t_);                            \
    if ((t_) + 4 < TT) {                                                      \
      const float4* s_ = (const float4*)(pb + (size_t)((t_) + 4) * TT);       \
      BK[0] = s_[lane];                                                       \
      BK[1] = s_[lane + 64];                                                  \
      BK[2] = s_[lane + 128];                                                 \
      BK[3] = s_[lane + 192];                                                 \
    }                                                                         \
  } while (0)

// ---------------- serial heavy-hitter scan: producer wave + consumer wave
__global__ __launch_bounds__(128) void k_scan(const float* __restrict__ p,
    const float* __restrict__ initacc, int* __restrict__ evict_g) {
  int bh = blockIdx.x;
  int tid = threadIdx.x;
  int lane = tid & 63;
  const float* pb = p + (size_t)bh * TT * TT;
  __shared__ float ring[RING][TT];
  __shared__ int ev[TT];
  __shared__ volatile int rdyf[RING];
  __shared__ volatile int donef;
  for (int i = tid; i < TT; i += 128) ev[i] = 0x7fffffff;
  if (tid < RING) rdyf[tid] = -1;
  if (tid == 0) donef = -1;
  __syncthreads();

  if (tid >= 64) {
    // ---------- producer: stream prob rows HB..TT-1 into the ring ----------
    float4 B0[4], B1[4], B2[4], B3[4];
    {
      const float4* s0 = (const float4*)(pb + (size_t)(HB + 0) * TT);
      const float4* s1 = (const float4*)(pb + (size_t)(HB + 1) * TT);
      const float4* s2 = (const float4*)(pb + (size_t)(HB + 2) * TT);
      const float4* s3 = (const float4*)(pb + (size_t)(HB + 3) * TT);
      #pragma unroll
      for (int j = 0; j < 4; ++j) {
        B0[j] = s0[lane + 64*j]; B1[j] = s1[lane + 64*j];
        B2[j] = s2[lane + 64*j]; B3[j] = s3[lane + 64*j];
      }
    }
    int t = HB;
    for (; t + 3 < TT; t += 4) {
      PROD_STEP(B0, t);
      PROD_STEP(B1, t + 1);
      PROD_STEP(B2, t + 2);
      PROD_STEP(B3, t + 3);
    }
    // remainder: rows 1021(B0), 1022(B1), 1023(B2)  [871 = 217*4 + 3]
    PROD_STEP(B0, 1021);
    PROD_STEP(B1, 1022);
    PROD_STEP(B2, 1023);
  } else {
    // ---------- consumer: serial scan, LDS-only critical path ----------
    bool act2 = lane < (HB - 128);   // lane < 25
    int col[3]; float sc[3];
    col[0] = lane;
    col[1] = 64 + lane;
    col[2] = act2 ? (128 + lane) : 0;
    sc[0] = initacc[(size_t)bh * 256 + lane];
    sc[1] = initacc[(size_t)bh * 256 + 64 + lane];
    sc[2] = act2 ? initacc[(size_t)bh * 256 + 128 + lane] : 0.f;
    int fpeek = -2;
    for (int t = HB; t < TT; ++t) {
      int slot = t & (RING - 1);
      if (fpeek != t) {
        while (rdyf[slot] != t) { }    // tight poll: fast wake
      }
      asm volatile("" ::: "memory");
      const float* rb = ring[slot];
      float r0 = rb[col[0]];
      float r1 = rb[col[1]];
      float r2 = rb[col[2]];
      float rd = rb[t];                       // diagonal prob p[t][t]
      fpeek = rdyf[(t + 1) & (RING - 1)];     // early peek for next step
      // keys from pre-update scores; min score evicted, tie -> larger col
      unsigned b0 = __float_as_uint(sc[0]);
      unsigned b1 = __float_as_uint(sc[1]);
      unsigned b2 = act2 ? __float_as_uint(sc[2]) : 0xFFFFFFFFu;
      unsigned mn = b0 < b1 ? b0 : b1; mn = mn < b2 ? mn : b2;
      unsigned mstar = wave_min_u32(mn);
      unsigned c0k = (b0 == mstar) ? (unsigned)(1023 - col[0]) : 0xFFFFFFFFu;
      unsigned c1k = (b1 == mstar) ? (unsigned)(1023 - col[1]) : 0xFFFFFFFFu;
      unsigned c2k = (act2 && b2 == mstar) ? (unsigned)(1023 - col[2]) : 0xFFFFFFFFu;
      unsigned cm = c0k < c1k ? c0k : c1k; cm = cm < c2k ? cm : c2k;
      int cstar = 1023 - (int)wave_min_u32(cm);
      if (b0 == mstar && col[0] == cstar) { ev[col[0]] = t; col[0] = t; sc[0] = rd; }
      else sc[0] += r0;
      if (b1 == mstar && col[1] == cstar) { ev[col[1]] = t; col[1] = t; sc[1] = rd; }
      else sc[1] += r1;
      if (act2) {
        if (b2 == mstar && col[2] == cstar) { ev[col[2]] = t; col[2] = t; sc[2] = rd; }
        else sc[2] += r2;
      }
      asm volatile("" ::: "memory");
      if (lane == 0 && (t & 3) == 3) donef = t;
    }
  }

  __syncthreads();
  int4* dst4 = (int4*)(evict_g + (size_t)bh * TT);
  const int4* src4 = (const int4*)ev;
  for (int i = tid; i < TT/4; i += 128) dst4[i] = src4[i];
}

// ---------------- masked renormalize + PV (p = probs)
__global__ __launch_bounds__(256) void k_attn(const float* __restrict__ p,
    const int* __restrict__ evict_g,
    const float* __restrict__ v, float* __restrict__ ao) {
  int bh = blockIdx.y, t = blockIdx.x;
  int tid = threadIdx.x;
  const float* row = p + ((size_t)bh * TT + t) * TT;
  __shared__ float pr[TT];
  __shared__ float red[4];
  __shared__ float pv[4][64];
  __shared__ int et[TT];
  ((int4*)et)[tid] = ((const int4*)(evict_g + (size_t)bh * TT))[tid];
  __syncthreads();

  float e[4];
  float s = 0.f;
  #pragma unroll
  for (int i = 0; i < 4; ++i) {
    int j = tid + 256*i;
    bool allow = (j <= t) && ((et[j] > t) || (j + RECW >= t));
    e[i] = allow ? row[j] : 0.f;
    s += e[i];
  }
  for (int o = 32; o; o >>= 1) s += __shfl_xor(s, o);
  int wid = tid >> 6;
  if ((tid & 63) == 0) red[wid] = s;
  __syncthreads();
  s = red[0] + red[1] + red[2] + red[3];
  float inv = 1.f / s;
  #pragma unroll
  for (int i = 0; i < 4; ++i) pr[tid + 256*i] = e[i] * inv;
  __syncthreads();

  int g = tid >> 6, d = tid & 63;
  const float* vb = v + (size_t)bh * TT * DD;
  float acc = 0.f;
  int lim = t + 1 - g*256; if (lim > 256) lim = 256;
  for (int i = 0; i < lim; ++i) {
    int j = g * 256 + i;
    acc += pr[j] * vb[(size_t)j * DD + d];
  }
  pv[g][d] = acc;
  __syncthreads();
  if (tid < 64) {
    float r = pv[0][tid] + pv[1][tid] + pv[2][tid] + pv[3][tid];
    int b_ = bh >> 4, h_ = bh & 15;
    ao[((size_t)b_ * TT + t) * EE + h_ * DD + tid] = r;
  }
}

extern "C" void kernel_launch(void* const* d_in, const int* in_sizes, int n_in,
                              void* d_out, int out_size, void* d_ws, size_t ws_size,
                              hipStream_t stream) {
  const float* hs = (const float*)d_in[0];
  const float* Wq = (const float*)d_in[2];
  const float* bq = (const float*)d_in[3];
  const float* Wk = (const float*)d_in[4];
  const float* bk = (const float*)d_in[5];
  const float* Wv = (const float*)d_in[6];
  const float* bv = (const float*)d_in[7];
  const float* Wo = (const float*)d_in[8];
  const float* bo = (const float*)d_in[9];
  float* out = (float*)d_out;

  float* ws = (float*)d_ws;
  float* q  = ws + OFF_Q;
  float* k  = ws + OFF_K;
  float* v  = ws + OFF_V;
  float* aw = ws + OFF_AW;   // becomes probs after k_softmax
  float* ao = ws + OFF_AO;
  float* initacc = ws + OFF_END;
  int* evict = (int*)(ws + OFF_END + (size_t)BHN * 256);

  dim3 gproj(16, 32);
  k_proj<<<gproj, 256, 0, stream>>>(hs, Wq, bq, q, 0.125f, 1);
  k_proj<<<gproj, 256, 0, stream>>>(hs, Wk, bk, k, 1.0f, 1);
  k_proj<<<gproj, 256, 0, stream>>>(hs, Wv, bv, v, 1.0f, 1);

  dim3 gqk(16, 16, BHN);
  k_qk<<<gqk, 256, 0, stream>>>(q, k, aw);

  dim3 grs(TT/4, BHN);
  k_softmax<<<grs, 256, 0, stream>>>(aw);

  k_init_acc<<<BHN, 256, 0, stream>>>(aw, initacc);

  k_scan<<<BHN, 128, 0, stream>>>(aw, initacc, evict);

  dim3 gat(TT, BHN);
  k_attn<<<gat, 256, 0, stream>>>(aw, evict, v, ao);

  k_proj<<<gproj, 256, 0, stream>>>(ao, Wo, bo, out, 1.0f, 0);
}

// Round 8
// 1051.518 us; speedup vs baseline: 1.3581x; 1.3358x over previous
//
#include <hip/hip_runtime.h>
#include <hip/hip_bf16.h>
#include <stdint.h>

#define TT 1024
#define EE 1024
#define HH 16
#define DD 64
#define BHN 32
#define HB 153
#define RECW 102
#define RING 8
#define INFLT 4
#define NEGF (-3.4028234663852886e38f)

typedef unsigned long long ull;

// workspace layout (float element offsets)
#define OFF_Q  ((size_t)0)
#define OFF_K  (OFF_Q + (size_t)BHN*TT*DD)
#define OFF_V  (OFF_K + (size_t)BHN*TT*DD)
#define OFF_AW (OFF_V + (size_t)BHN*TT*DD)
#define OFF_M  (OFF_AW + (size_t)BHN*TT*TT)
#define OFF_S  (OFF_M + (size_t)BHN*TT)
#define OFF_AO (OFF_S + (size_t)BHN*TT)
#define OFF_END (OFF_AO + (size_t)BHN*TT*DD)
// after OFF_END: initacc float[BHN*256], evict int[BHN*1024]

// ---------------- GEMM: Y = X @ W + b (optionally scaled, optionally head-split store)
__global__ __launch_bounds__(256) void k_proj(const float* __restrict__ X,
    const float* __restrict__ W, const float* __restrict__ bias,
    float* __restrict__ Y, float scale, int headsplit) {
  __shared__ float As[64][17];
  __shared__ float Bs[16][65];
  int tid = threadIdx.x;
  int tx = tid & 15, ty = tid >> 4;
  int r0 = blockIdx.y * 64, c0 = blockIdx.x * 64;
  float acc[4][4] = {};
  for (int k0 = 0; k0 < EE; k0 += 16) {
    {
      int i = tid >> 2;
      int kk = (tid & 3) * 4;
      const float4 a = *(const float4*)&X[(size_t)(r0 + i) * EE + k0 + kk];
      As[i][kk] = a.x; As[i][kk+1] = a.y; As[i][kk+2] = a.z; As[i][kk+3] = a.w;
    }
    {
      int kk = tid >> 4;
      int j = (tid & 15) * 4;
      const float4 b = *(const float4*)&W[(size_t)(k0 + kk) * EE + c0 + j];
      Bs[kk][j] = b.x; Bs[kk][j+1] = b.y; Bs[kk][j+2] = b.z; Bs[kk][j+3] = b.w;
    }
    __syncthreads();
    #pragma unroll
    for (int kk = 0; kk < 16; ++kk) {
      float a[4], b[4];
      #pragma unroll
      for (int u = 0; u < 4; ++u) a[u] = As[ty*4+u][kk];
      #pragma unroll
      for (int v = 0; v < 4; ++v) b[v] = Bs[kk][tx*4+v];
      #pragma unroll
      for (int u = 0; u < 4; ++u)
        #pragma unroll
        for (int v = 0; v < 4; ++v) acc[u][v] += a[u]*b[v];
    }
    __syncthreads();
  }
  #pragma unroll
  for (int u = 0; u < 4; ++u) {
    int r = r0 + ty*4 + u;
    #pragma unroll
    for (int v = 0; v < 4; ++v) {
      int c = c0 + tx*4 + v;
      float val = (acc[u][v] + bias[c]) * scale;
      if (headsplit) {
        int b_ = r >> 10, t_ = r & 1023, h_ = c >> 6, d_ = c & 63;
        Y[(((size_t)(b_*HH + h_) * TT) + t_) * DD + d_] = val;
      } else {
        Y[(size_t)r * EE + c] = val;
      }
    }
  }
}

// ---------------- batched QK^T
__global__ __launch_bounds__(256) void k_qk(const float* __restrict__ q,
    const float* __restrict__ k, float* __restrict__ aw) {
  int bh = blockIdx.z;
  int t0 = blockIdx.y * 64, s0 = blockIdx.x * 64;
  if (s0 > t0 + 63) return;
  __shared__ float Qs[64][65];
  __shared__ float Ks[64][65];
  int tid = threadIdx.x;
  const float* qb = q + (size_t)bh * TT * DD;
  const float* kb = k + (size_t)bh * TT * DD;
  #pragma unroll
  for (int u = 0; u < 4; ++u) {
    int fi = tid + u * 256;
    int row = fi >> 4, c4 = (fi & 15) * 4;
    float4 a = *(const float4*)&qb[(size_t)(t0 + row) * DD + c4];
    Qs[row][c4] = a.x; Qs[row][c4+1] = a.y; Qs[row][c4+2] = a.z; Qs[row][c4+3] = a.w;
    float4 b = *(const float4*)&kb[(size_t)(s0 + row) * DD + c4];
    Ks[row][c4] = b.x; Ks[row][c4+1] = b.y; Ks[row][c4+2] = b.z; Ks[row][c4+3] = b.w;
  }
  __syncthreads();
  int tx = tid & 15, ty = tid >> 4;
  float acc[4][4] = {};
  #pragma unroll 8
  for (int kk = 0; kk < 64; ++kk) {
    float a[4], b[4];
    #pragma unroll
    for (int u = 0; u < 4; ++u) a[u] = Qs[ty*4+u][kk];
    #pragma unroll
    for (int v = 0; v < 4; ++v) b[v] = Ks[tx*4+v][kk];
    #pragma unroll
    for (int u = 0; u < 4; ++u)
      #pragma unroll
      for (int v = 0; v < 4; ++v) acc[u][v] += a[u]*b[v];
  }
  float* awb = aw + (size_t)bh * TT * TT;
  #pragma unroll
  for (int u = 0; u < 4; ++u) {
    int t_ = t0 + ty*4 + u;
    #pragma unroll
    for (int v = 0; v < 4; ++v)
      awb[(size_t)t_ * TT + s0 + tx*4 + v] = acc[u][v];
  }
}

// ---------------- row softmax in place: aw row -> probs (lower triangle only)
__global__ __launch_bounds__(256) void k_softmax(float* __restrict__ aw) {
  int bh = blockIdx.y;
  int wid = threadIdx.x >> 6, lane = threadIdx.x & 63;
  int t = blockIdx.x * 4 + wid;
  float* row = aw + ((size_t)bh * TT + t) * TT;
  float vals[16];
  float m = NEGF;
  #pragma unroll
  for (int i = 0; i < 16; ++i) {
    int j = lane + 64*i;
    vals[i] = (j <= t) ? row[j] : NEGF;
    m = fmaxf(m, vals[i]);
  }
  for (int o = 32; o; o >>= 1) m = fmaxf(m, __shfl_xor(m, o));
  float s = 0.f;
  #pragma unroll
  for (int i = 0; i < 16; ++i) {
    int j = lane + 64*i;
    if (j <= t) { vals[i] = expf(vals[i] - m); s += vals[i]; }
  }
  for (int o = 32; o; o >>= 1) s += __shfl_xor(s, o);
  float inv = 1.0f / s;
  #pragma unroll
  for (int i = 0; i < 16; ++i) {
    int j = lane + 64*i;
    if (j <= t) row[j] = vals[i] * inv;
  }
}

// ---------------- parallel init of heavy-hitter scores (p = probs)
__global__ __launch_bounds__(256) void k_init_acc(const float* __restrict__ p,
    float* __restrict__ initacc) {
  int bh = blockIdx.x;
  int c = threadIdx.x;
  float val = 0.f;
  if (c < HB) {
    const float* pb = p + (size_t)bh * TT * TT;
    for (int i = c; i < HB; ++i)
      val += pb[(size_t)i * TT + c];
  }
  initacc[(size_t)bh * 256 + c] = val;
}

// ---------------- wave-wide min over u32 via DPP (VALU path, no LDS)
#define DPP_HOP(ctrl)                                                        \
  {                                                                          \
    unsigned tt = (unsigned)__builtin_amdgcn_update_dpp(                     \
        (int)0xFFFFFFFFu, (int)x, (ctrl), 0xF, 0xF, false);                  \
    x = x < tt ? x : tt;                                                     \
  }
__device__ __forceinline__ unsigned wave_min_u32(unsigned x) {
  DPP_HOP(0x111)  // row_shr:1
  DPP_HOP(0x112)  // row_shr:2
  DPP_HOP(0x114)  // row_shr:4
  DPP_HOP(0x118)  // row_shr:8
  DPP_HOP(0x142)  // row_bcast:15
  DPP_HOP(0x143)  // row_bcast:31
  return (unsigned)__builtin_amdgcn_readlane((int)x, 63);
}

// global -> LDS direct DMA, 16B per lane. gsrc: PER-LANE global addr;
// ldst: WAVE-UNIFORM lds base (HW adds lane*16).
__device__ __forceinline__ void gload_lds16(const float* gsrc, float* ldst) {
  __builtin_amdgcn_global_load_lds(
      (const __attribute__((address_space(1))) unsigned int*)gsrc,
      (__attribute__((address_space(3))) unsigned int*)ldst,
      16, 0, 0);
}

// ---------------- serial heavy-hitter scan: DMA producer wave + consumer wave
// Producer keeps INFLT=4 rows (16 loads) in flight; literal s_waitcnt vmcnt(12)
// at the top of each iteration guarantees the OLDEST row landed (exactly 4
// loads issued per iteration, including tail garbage-refetches). Consumer
// publishes donef EVERY step; producer overwrites slot rn&7 (holding row
// rn-RING) only after donef >= rn-RING => 4 rows of slack, no circular wait.
// Tail (rn >= TT): garbage refetch of row TT-1 lands in ring[rn&7], which the
// consumer is provably done with (donef wait above) and never reads again —
// NO separate dummy buffer (round 7's dummy was 1KB but received 4KB -> LDS
// overflow clobbered the flags -> hang).
__global__ __launch_bounds__(128) void k_scan(const float* __restrict__ p,
    const float* __restrict__ initacc, int* __restrict__ evict_g) {
  int bh = blockIdx.x;
  int tid = threadIdx.x;
  int lane = tid & 63;
  const float* pb = p + (size_t)bh * TT * TT;
  __shared__ float ring[RING][TT];
  __shared__ int ev[TT];
  __shared__ volatile int rdyf[RING];
  __shared__ volatile int donef;
  for (int i = tid; i < TT; i += 128) ev[i] = 0x7fffffff;
  if (tid < RING) rdyf[tid] = -1;
  if (tid == 0) donef = -1;
  __syncthreads();

  if (tid >= 64) {
    // ---------- producer: pure DMA via global_load_lds, counted vmcnt ----------
    #pragma unroll
    for (int r = 0; r < INFLT; ++r) {
      const float* srcrow = pb + (size_t)(HB + r) * TT;
      float* slotbase = ring[(HB + r) & (RING - 1)];
      #pragma unroll
      for (int j = 0; j < 4; ++j)
        gload_lds16(srcrow + j * 256 + lane * 4, slotbase + j * 256);
    }
    for (int r = HB; r < TT; ++r) {
      // oldest outstanding row (= r) has landed after this wait
      asm volatile("s_waitcnt vmcnt(12)" ::: "memory");
      if (lane == 0) rdyf[r & (RING - 1)] = r;
      int rn = r + INFLT;
      // slot rn&7 holds row rn-RING; wait until consumer is done with it
      if (rn - RING >= HB) {
        while (donef < rn - RING) { }
      }
      // tail: rn>=TT -> refetch row TT-1 into the (consumer-dead) slot rn&7
      int rsrc = rn < TT ? rn : TT - 1;
      const float* srcrow = pb + (size_t)rsrc * TT;
      float* slotbase = ring[rn & (RING - 1)];
      #pragma unroll
      for (int j = 0; j < 4; ++j)
        gload_lds16(srcrow + j * 256 + lane * 4, slotbase + j * 256);
    }
  } else {
    // ---------- consumer: serial scan, LDS-only critical path ----------
    bool act2 = lane < (HB - 128);   // lane < 25
    int col[3]; float sc[3];
    col[0] = lane;
    col[1] = 64 + lane;
    col[2] = act2 ? (128 + lane) : 0;
    sc[0] = initacc[(size_t)bh * 256 + lane];
    sc[1] = initacc[(size_t)bh * 256 + 64 + lane];
    sc[2] = act2 ? initacc[(size_t)bh * 256 + 128 + lane] : 0.f;
    int fpeek = -2;
    for (int t = HB; t < TT; ++t) {
      int slot = t & (RING - 1);
      if (fpeek != t) {
        while (rdyf[slot] != t) { }    // tight poll: fast wake
      }
      asm volatile("" ::: "memory");
      const float* rb = ring[slot];
      float r0 = rb[col[0]];
      float r1 = rb[col[1]];
      float r2 = rb[col[2]];
      float rd = rb[t];                       // diagonal prob p[t][t]
      fpeek = rdyf[(t + 1) & (RING - 1)];     // early peek for next step
      // keys from pre-update scores; min score evicted, tie -> larger col
      unsigned b0 = __float_as_uint(sc[0]);
      unsigned b1 = __float_as_uint(sc[1]);
      unsigned b2 = act2 ? __float_as_uint(sc[2]) : 0xFFFFFFFFu;
      unsigned mn = b0 < b1 ? b0 : b1; mn = mn < b2 ? mn : b2;
      unsigned mstar = wave_min_u32(mn);
      unsigned c0k = (b0 == mstar) ? (unsigned)(1023 - col[0]) : 0xFFFFFFFFu;
      unsigned c1k = (b1 == mstar) ? (unsigned)(1023 - col[1]) : 0xFFFFFFFFu;
      unsigned c2k = (act2 && b2 == mstar) ? (unsigned)(1023 - col[2]) : 0xFFFFFFFFu;
      unsigned cm = c0k < c1k ? c0k : c1k; cm = cm < c2k ? cm : c2k;
      int cstar = 1023 - (int)wave_min_u32(cm);
      if (b0 == mstar && col[0] == cstar) { ev[col[0]] = t; col[0] = t; sc[0] = rd; }
      else sc[0] += r0;
      if (b1 == mstar && col[1] == cstar) { ev[col[1]] = t; col[1] = t; sc[1] = rd; }
      else sc[1] += r1;
      if (act2) {
        if (b2 == mstar && col[2] == cstar) { ev[col[2]] = t; col[2] = t; sc[2] = rd; }
        else sc[2] += r2;
      }
      asm volatile("" ::: "memory");
      if (lane == 0) donef = t;     // publish EVERY step
    }
  }

  __syncthreads();
  int4* dst4 = (int4*)(evict_g + (size_t)bh * TT);
  const int4* src4 = (const int4*)ev;
  for (int i = tid; i < TT/4; i += 128) dst4[i] = src4[i];
}

// ---------------- masked renormalize + PV (p = probs)
__global__ __launch_bounds__(256) void k_attn(const float* __restrict__ p,
    const int* __restrict__ evict_g,
    const float* __restrict__ v, float* __restrict__ ao) {
  int bh = blockIdx.y, t = blockIdx.x;
  int tid = threadIdx.x;
  const float* row = p + ((size_t)bh * TT + t) * TT;
  __shared__ float pr[TT];
  __shared__ float red[4];
  __shared__ float pv[4][64];
  __shared__ int et[TT];
  ((int4*)et)[tid] = ((const int4*)(evict_g + (size_t)bh * TT))[tid];
  __syncthreads();

  float e[4];
  float s = 0.f;
  #pragma unroll
  for (int i = 0; i < 4; ++i) {
    int j = tid + 256*i;
    bool allow = (j <= t) && ((et[j] > t) || (j + RECW >= t));
    e[i] = allow ? row[j] : 0.f;
    s += e[i];
  }
  for (int o = 32; o; o >>= 1) s += __shfl_xor(s, o);
  int wid = tid >> 6;
  if ((tid & 63) == 0) red[wid] = s;
  __syncthreads();
  s = red[0] + red[1] + red[2] + red[3];
  float inv = 1.f / s;
  #pragma unroll
  for (int i = 0; i < 4; ++i) pr[tid + 256*i] = e[i] * inv;
  __syncthreads();

  int g = tid >> 6, d = tid & 63;
  const float* vb = v + (size_t)bh * TT * DD;
  float acc = 0.f;
  int lim = t + 1 - g*256; if (lim > 256) lim = 256;
  for (int i = 0; i < lim; ++i) {
    int j = g * 256 + i;
    acc += pr[j] * vb[(size_t)j * DD + d];
  }
  pv[g][d] = acc;
  __syncthreads();
  if (tid < 64) {
    float r = pv[0][tid] + pv[1][tid] + pv[2][tid] + pv[3][tid];
    int b_ = bh >> 4, h_ = bh & 15;
    ao[((size_t)b_ * TT + t) * EE + h_ * DD + tid] = r;
  }
}

extern "C" void kernel_launch(void* const* d_in, const int* in_sizes, int n_in,
                              void* d_out, int out_size, void* d_ws, size_t ws_size,
                              hipStream_t stream) {
  const float* hs = (const float*)d_in[0];
  const float* Wq = (const float*)d_in[2];
  const float* bq = (const float*)d_in[3];
  const float* Wk = (const float*)d_in[4];
  const float* bk = (const float*)d_in[5];
  const float* Wv = (const float*)d_in[6];
  const float* bv = (const float*)d_in[7];
  const float* Wo = (const float*)d_in[8];
  const float* bo = (const float*)d_in[9];
  float* out = (float*)d_out;

  float* ws = (float*)d_ws;
  float* q  = ws + OFF_Q;
  float* k  = ws + OFF_K;
  float* v  = ws + OFF_V;
  float* aw = ws + OFF_AW;   // becomes probs after k_softmax
  float* ao = ws + OFF_AO;
  float* initacc = ws + OFF_END;
  int* evict = (int*)(ws + OFF_END + (size_t)BHN * 256);

  dim3 gproj(16, 32);
  k_proj<<<gproj, 256, 0, stream>>>(hs, Wq, bq, q, 0.125f, 1);
  k_proj<<<gproj, 256, 0, stream>>>(hs, Wk, bk, k, 1.0f, 1);
  k_proj<<<gproj, 256, 0, stream>>>(hs, Wv, bv, v, 1.0f, 1);

  dim3 gqk(16, 16, BHN);
  k_qk<<<gqk, 256, 0, stream>>>(q, k, aw);

  dim3 grs(TT/4, BHN);
  k_softmax<<<grs, 256, 0, stream>>>(aw);

  k_init_acc<<<BHN, 256, 0, stream>>>(aw, initacc);

  k_scan<<<BHN, 128, 0, stream>>>(aw, initacc, evict);

  dim3 gat(TT, BHN);
  k_attn<<<gat, 256, 0, stream>>>(aw, evict, v, ao);

  k_proj<<<gproj, 256, 0, stream>>>(ao, Wo, bo, out, 1.0f, 0);
}

// Round 9
// 925.561 us; speedup vs baseline: 1.5429x; 1.1361x over previous
//
#include <hip/hip_runtime.h>
#include <hip/hip_bf16.h>
#include <stdint.h>

#define TT 1024
#define EE 1024
#define HH 16
#define DD 64
#define BHN 32
#define HB 153
#define RECW 102
#define RING 8
#define INFLT 4
#define NEGF (-3.4028234663852886e38f)

typedef unsigned long long ull;
typedef __attribute__((ext_vector_type(8))) short bf16x8;
typedef __attribute__((ext_vector_type(4))) float f32x4;

// workspace layout (float element offsets)
#define OFF_Q  ((size_t)0)
#define OFF_K  (OFF_Q + (size_t)BHN*TT*DD)
#define OFF_V  (OFF_K + (size_t)BHN*TT*DD)   // reused as bf16 (ushort) buffer
#define OFF_AW (OFF_V + (size_t)BHN*TT*DD)
#define OFF_M  (OFF_AW + (size_t)BHN*TT*TT)
#define OFF_S  (OFF_M + (size_t)BHN*TT)
#define OFF_AO (OFF_S + (size_t)BHN*TT)
#define OFF_END (OFF_AO + (size_t)BHN*TT*DD)
// after OFF_END: initacc float[BHN*256], evict int[BHN*1024]

__device__ __forceinline__ ushort f2bf(float x) {
  unsigned u = __float_as_uint(x);
  u = (u + 0x7FFF + ((u >> 16) & 1)) >> 16;   // RNE
  return (ushort)u;
}

// ---------------- GEMM: Y = X @ W + b. headsplit: 0=flat f32, 1=headsplit f32, 2=headsplit bf16
__global__ __launch_bounds__(256) void k_proj(const float* __restrict__ X,
    const float* __restrict__ W, const float* __restrict__ bias,
    float* __restrict__ Y, float scale, int headsplit) {
  __shared__ float As[64][17];
  __shared__ float Bs[16][65];
  int tid = threadIdx.x;
  int tx = tid & 15, ty = tid >> 4;
  int r0 = blockIdx.y * 64, c0 = blockIdx.x * 64;
  float acc[4][4] = {};
  for (int k0 = 0; k0 < EE; k0 += 16) {
    {
      int i = tid >> 2;
      int kk = (tid & 3) * 4;
      const float4 a = *(const float4*)&X[(size_t)(r0 + i) * EE + k0 + kk];
      As[i][kk] = a.x; As[i][kk+1] = a.y; As[i][kk+2] = a.z; As[i][kk+3] = a.w;
    }
    {
      int kk = tid >> 4;
      int j = (tid & 15) * 4;
      const float4 b = *(const float4*)&W[(size_t)(k0 + kk) * EE + c0 + j];
      Bs[kk][j] = b.x; Bs[kk][j+1] = b.y; Bs[kk][j+2] = b.z; Bs[kk][j+3] = b.w;
    }
    __syncthreads();
    #pragma unroll
    for (int kk = 0; kk < 16; ++kk) {
      float a[4], b[4];
      #pragma unroll
      for (int u = 0; u < 4; ++u) a[u] = As[ty*4+u][kk];
      #pragma unroll
      for (int v = 0; v < 4; ++v) b[v] = Bs[kk][tx*4+v];
      #pragma unroll
      for (int u = 0; u < 4; ++u)
        #pragma unroll
        for (int v = 0; v < 4; ++v) acc[u][v] += a[u]*b[v];
    }
    __syncthreads();
  }
  #pragma unroll
  for (int u = 0; u < 4; ++u) {
    int r = r0 + ty*4 + u;
    #pragma unroll
    for (int v = 0; v < 4; ++v) {
      int c = c0 + tx*4 + v;
      float val = (acc[u][v] + bias[c]) * scale;
      int b_ = r >> 10, t_ = r & 1023, h_ = c >> 6, d_ = c & 63;
      if (headsplit == 1) {
        Y[(((size_t)(b_*HH + h_) * TT) + t_) * DD + d_] = val;
      } else if (headsplit == 2) {
        ((ushort*)Y)[(((size_t)(b_*HH + h_) * TT) + t_) * DD + d_] = f2bf(val);
      } else {
        Y[(size_t)r * EE + c] = val;
      }
    }
  }
}

// ---------------- batched QK^T
__global__ __launch_bounds__(256) void k_qk(const float* __restrict__ q,
    const float* __restrict__ k, float* __restrict__ aw) {
  int bh = blockIdx.z;
  int t0 = blockIdx.y * 64, s0 = blockIdx.x * 64;
  if (s0 > t0 + 63) return;
  __shared__ float Qs[64][65];
  __shared__ float Ks[64][65];
  int tid = threadIdx.x;
  const float* qb = q + (size_t)bh * TT * DD;
  const float* kb = k + (size_t)bh * TT * DD;
  #pragma unroll
  for (int u = 0; u < 4; ++u) {
    int fi = tid + u * 256;
    int row = fi >> 4, c4 = (fi & 15) * 4;
    float4 a = *(const float4*)&qb[(size_t)(t0 + row) * DD + c4];
    Qs[row][c4] = a.x; Qs[row][c4+1] = a.y; Qs[row][c4+2] = a.z; Qs[row][c4+3] = a.w;
    float4 b = *(const float4*)&kb[(size_t)(s0 + row) * DD + c4];
    Ks[row][c4] = b.x; Ks[row][c4+1] = b.y; Ks[row][c4+2] = b.z; Ks[row][c4+3] = b.w;
  }
  __syncthreads();
  int tx = tid & 15, ty = tid >> 4;
  float acc[4][4] = {};
  #pragma unroll 8
  for (int kk = 0; kk < 64; ++kk) {
    float a[4], b[4];
    #pragma unroll
    for (int u = 0; u < 4; ++u) a[u] = Qs[ty*4+u][kk];
    #pragma unroll
    for (int v = 0; v < 4; ++v) b[v] = Ks[tx*4+v][kk];
    #pragma unroll
    for (int u = 0; u < 4; ++u)
      #pragma unroll
      for (int v = 0; v < 4; ++v) acc[u][v] += a[u]*b[v];
  }
  float* awb = aw + (size_t)bh * TT * TT;
  #pragma unroll
  for (int u = 0; u < 4; ++u) {
    int t_ = t0 + ty*4 + u;
    #pragma unroll
    for (int v = 0; v < 4; ++v)
      awb[(size_t)t_ * TT + s0 + tx*4 + v] = acc[u][v];
  }
}

// ---------------- row softmax in place: aw row -> probs (lower triangle only)
__global__ __launch_bounds__(256) void k_softmax(float* __restrict__ aw) {
  int bh = blockIdx.y;
  int wid = threadIdx.x >> 6, lane = threadIdx.x & 63;
  int t = blockIdx.x * 4 + wid;
  float* row = aw + ((size_t)bh * TT + t) * TT;
  float vals[16];
  float m = NEGF;
  #pragma unroll
  for (int i = 0; i < 16; ++i) {
    int j = lane + 64*i;
    vals[i] = (j <= t) ? row[j] : NEGF;
    m = fmaxf(m, vals[i]);
  }
  for (int o = 32; o; o >>= 1) m = fmaxf(m, __shfl_xor(m, o));
  float s = 0.f;
  #pragma unroll
  for (int i = 0; i < 16; ++i) {
    int j = lane + 64*i;
    if (j <= t) { vals[i] = expf(vals[i] - m); s += vals[i]; }
  }
  for (int o = 32; o; o >>= 1) s += __shfl_xor(s, o);
  float inv = 1.0f / s;
  #pragma unroll
  for (int i = 0; i < 16; ++i) {
    int j = lane + 64*i;
    if (j <= t) row[j] = vals[i] * inv;
  }
}

// ---------------- parallel init of heavy-hitter scores (p = probs)
__global__ __launch_bounds__(256) void k_init_acc(const float* __restrict__ p,
    float* __restrict__ initacc) {
  int bh = blockIdx.x;
  int c = threadIdx.x;
  float val = 0.f;
  if (c < HB) {
    const float* pb = p + (size_t)bh * TT * TT;
    for (int i = c; i < HB; ++i)
      val += pb[(size_t)i * TT + c];
  }
  initacc[(size_t)bh * 256 + c] = val;
}

// ---------------- wave-wide min over u32 via DPP (VALU path, no LDS)
#define DPP_HOP(ctrl)                                                        \
  {                                                                          \
    unsigned tt = (unsigned)__builtin_amdgcn_update_dpp(                     \
        (int)0xFFFFFFFFu, (int)x, (ctrl), 0xF, 0xF, false);                  \
    x = x < tt ? x : tt;                                                     \
  }
__device__ __forceinline__ unsigned wave_min_u32(unsigned x) {
  DPP_HOP(0x111)  // row_shr:1
  DPP_HOP(0x112)  // row_shr:2
  DPP_HOP(0x114)  // row_shr:4
  DPP_HOP(0x118)  // row_shr:8
  DPP_HOP(0x142)  // row_bcast:15
  DPP_HOP(0x143)  // row_bcast:31
  return (unsigned)__builtin_amdgcn_readlane((int)x, 63);
}

// global -> LDS direct DMA, 16B per lane
__device__ __forceinline__ void gload_lds16(const float* gsrc, float* ldst) {
  __builtin_amdgcn_global_load_lds(
      (const __attribute__((address_space(1))) unsigned int*)gsrc,
      (__attribute__((address_space(3))) unsigned int*)ldst,
      16, 0, 0);
}

// ---------------- serial heavy-hitter scan: DMA producer wave + consumer wave
__global__ __launch_bounds__(128) void k_scan(const float* __restrict__ p,
    const float* __restrict__ initacc, int* __restrict__ evict_g) {
  int bh = blockIdx.x;
  int tid = threadIdx.x;
  int lane = tid & 63;
  const float* pb = p + (size_t)bh * TT * TT;
  __shared__ float ring[RING][TT];
  __shared__ int ev[TT];
  __shared__ volatile int rdyf[RING];
  __shared__ volatile int donef;
  for (int i = tid; i < TT; i += 128) ev[i] = 0x7fffffff;
  if (tid < RING) rdyf[tid] = -1;
  if (tid == 0) donef = -1;
  __syncthreads();

  if (tid >= 64) {
    // ---------- producer: pure DMA via global_load_lds, counted vmcnt ----------
    #pragma unroll
    for (int r = 0; r < INFLT; ++r) {
      const float* srcrow = pb + (size_t)(HB + r) * TT;
      float* slotbase = ring[(HB + r) & (RING - 1)];
      #pragma unroll
      for (int j = 0; j < 4; ++j)
        gload_lds16(srcrow + j * 256 + lane * 4, slotbase + j * 256);
    }
    for (int r = HB; r < TT; ++r) {
      asm volatile("s_waitcnt vmcnt(12)" ::: "memory");
      if (lane == 0) rdyf[r & (RING - 1)] = r;
      int rn = r + INFLT;
      if (rn - RING >= HB) {
        while (donef < rn - RING) { }
      }
      int rsrc = rn < TT ? rn : TT - 1;
      const float* srcrow = pb + (size_t)rsrc * TT;
      float* slotbase = ring[rn & (RING - 1)];
      #pragma unroll
      for (int j = 0; j < 4; ++j)
        gload_lds16(srcrow + j * 256 + lane * 4, slotbase + j * 256);
    }
  } else {
    // ---------- consumer: serial scan, LDS-only critical path ----------
    bool act2 = lane < (HB - 128);   // lane < 25
    int col[3]; float sc[3];
    col[0] = lane;
    col[1] = 64 + lane;
    col[2] = act2 ? (128 + lane) : 0;
    sc[0] = initacc[(size_t)bh * 256 + lane];
    sc[1] = initacc[(size_t)bh * 256 + 64 + lane];
    sc[2] = act2 ? initacc[(size_t)bh * 256 + 128 + lane] : 0.f;
    int fpeek = -2;
    for (int t = HB; t < TT; ++t) {
      int slot = t & (RING - 1);
      if (fpeek != t) {
        while (rdyf[slot] != t) { }
      }
      asm volatile("" ::: "memory");
      const float* rb = ring[slot];
      float r0 = rb[col[0]];
      float r1 = rb[col[1]];
      float r2 = rb[col[2]];
      float rd = rb[t];
      fpeek = rdyf[(t + 1) & (RING - 1)];
      unsigned b0 = __float_as_uint(sc[0]);
      unsigned b1 = __float_as_uint(sc[1]);
      unsigned b2 = act2 ? __float_as_uint(sc[2]) : 0xFFFFFFFFu;
      unsigned mn = b0 < b1 ? b0 : b1; mn = mn < b2 ? mn : b2;
      unsigned mstar = wave_min_u32(mn);
      unsigned c0k = (b0 == mstar) ? (unsigned)(1023 - col[0]) : 0xFFFFFFFFu;
      unsigned c1k = (b1 == mstar) ? (unsigned)(1023 - col[1]) : 0xFFFFFFFFu;
      unsigned c2k = (act2 && b2 == mstar) ? (unsigned)(1023 - col[2]) : 0xFFFFFFFFu;
      unsigned cm = c0k < c1k ? c0k : c1k; cm = cm < c2k ? cm : c2k;
      int cstar = 1023 - (int)wave_min_u32(cm);
      if (b0 == mstar && col[0] == cstar) { ev[col[0]] = t; col[0] = t; sc[0] = rd; }
      else sc[0] += r0;
      if (b1 == mstar && col[1] == cstar) { ev[col[1]] = t; col[1] = t; sc[1] = rd; }
      else sc[1] += r1;
      if (act2) {
        if (b2 == mstar && col[2] == cstar) { ev[col[2]] = t; col[2] = t; sc[2] = rd; }
        else sc[2] += r2;
      }
      asm volatile("" ::: "memory");
      if (lane == 0) donef = t;
    }
  }

  __syncthreads();
  int4* dst4 = (int4*)(evict_g + (size_t)bh * TT);
  const int4* src4 = (const int4*)ev;
  for (int i = tid; i < TT/4; i += 128) dst4[i] = src4[i];
}

// ---------------- fused mask + renorm + PV via bf16 MFMA
// out[t,d] = ( sum_j mask(t,j) * p[t,j]_bf16 * V[j,d]_bf16 ) / sum_j mask(t,j)*p[t,j]_f32
__global__ __launch_bounds__(256) void k_pv(const float* __restrict__ p,
    const int* __restrict__ evict_g, const ushort* __restrict__ vbf,
    float* __restrict__ ao) {
  int bh = blockIdx.y, tt = blockIdx.x;
  int tid = threadIdx.x, lane = tid & 63, wid = tid >> 6;
  int t0 = tt * 64;
  __shared__ ushort PA[64][72];   // masked bf16 P tile (pad: 144B row stride)
  __shared__ ushort VT[64][72];   // V tile transposed: VT[d][s]
  __shared__ float rowsum[64];
  __shared__ int et[TT];
  ((int4*)et)[tid] = ((const int4*)(evict_g + (size_t)bh * TT))[tid];
  if (tid < 64) rowsum[tid] = 0.f;
  const float* pb = p + ((size_t)bh * TT + t0) * TT;
  const ushort* vb = vbf + (size_t)bh * TT * DD;

  f32x4 acc[4];
  #pragma unroll
  for (int nc = 0; nc < 4; ++nc) acc[nc] = (f32x4){0.f, 0.f, 0.f, 0.f};

  int r = tid >> 2;             // 0..63 (row of P tile / s-row of V tile)
  int c0 = (tid & 3) * 16;      // 0,16,32,48
  int tg = t0 + r;
  __syncthreads();

  for (int st = 0; st <= tt; ++st) {
    // ---- stage masked P tile (fp32 -> bf16) + exact fp32 row sums ----
    const float* prow = pb + (size_t)r * TT + st * 64 + c0;
    float part = 0.f;
    ushort tmp16[16];
    #pragma unroll
    for (int q4 = 0; q4 < 4; ++q4) {
      float4 pv4 = *(const float4*)(prow + q4 * 4);
      float vals[4] = {pv4.x, pv4.y, pv4.z, pv4.w};
      #pragma unroll
      for (int u = 0; u < 4; ++u) {
        int j = st * 64 + c0 + q4 * 4 + u;
        bool allow = (j <= tg) && ((et[j] > tg) || (j + RECW >= tg));
        float mv = allow ? vals[u] : 0.f;
        part += mv;
        tmp16[q4 * 4 + u] = f2bf(mv);
      }
    }
    #pragma unroll
    for (int w2 = 0; w2 < 8; ++w2) {
      unsigned pk = (unsigned)tmp16[w2 * 2] | ((unsigned)tmp16[w2 * 2 + 1] << 16);
      *(unsigned*)&PA[r][c0 + w2 * 2] = pk;
    }
    part += __shfl_xor(part, 1);
    part += __shfl_xor(part, 2);
    if ((tid & 3) == 0) rowsum[r] += part;
    // ---- stage V tile transposed ----
    {
      const unsigned* vrow32 = (const unsigned*)(vb + (size_t)(st * 64 + r) * DD + c0);
      #pragma unroll
      for (int u = 0; u < 8; ++u) {
        unsigned vv = vrow32[u];
        VT[c0 + u * 2][r] = (ushort)(vv & 0xFFFF);
        VT[c0 + u * 2 + 1][r] = (ushort)(vv >> 16);
      }
    }
    __syncthreads();
    // ---- MFMA: wave wid -> output rows [wid*16, wid*16+16), all 4 col blocks ----
    #pragma unroll
    for (int kb = 0; kb < 2; ++kb) {
      bf16x8 af = *(const bf16x8*)&PA[wid * 16 + (lane & 15)][kb * 32 + (lane >> 4) * 8];
      #pragma unroll
      for (int nc = 0; nc < 4; ++nc) {
        bf16x8 bfr = *(const bf16x8*)&VT[nc * 16 + (lane & 15)][kb * 32 + (lane >> 4) * 8];
        acc[nc] = __builtin_amdgcn_mfma_f32_16x16x32_bf16(af, bfr, acc[nc], 0, 0, 0);
      }
    }
    __syncthreads();
  }

  // ---- scale by 1/rowsum and store head-split into ao ----
  int b_ = bh >> 4, h_ = bh & 15;
  int rl = wid * 16 + (lane >> 4) * 4;
  #pragma unroll
  for (int nc = 0; nc < 4; ++nc) {
    int d = nc * 16 + (lane & 15);
    #pragma unroll
    for (int qq = 0; qq < 4; ++qq) {
      int rr = rl + qq;
      float outv = acc[nc][qq] / rowsum[rr];
      ao[((size_t)b_ * TT + (t0 + rr)) * EE + h_ * DD + d] = outv;
    }
  }
}

extern "C" void kernel_launch(void* const* d_in, const int* in_sizes, int n_in,
                              void* d_out, int out_size, void* d_ws, size_t ws_size,
                              hipStream_t stream) {
  const float* hs = (const float*)d_in[0];
  const float* Wq = (const float*)d_in[2];
  const float* bq = (const float*)d_in[3];
  const float* Wk = (const float*)d_in[4];
  const float* bk = (const float*)d_in[5];
  const float* Wv = (const float*)d_in[6];
  const float* bv = (const float*)d_in[7];
  const float* Wo = (const float*)d_in[8];
  const float* bo = (const float*)d_in[9];
  float* out = (float*)d_out;

  float* ws = (float*)d_ws;
  float* q  = ws + OFF_Q;
  float* k  = ws + OFF_K;
  float* v  = ws + OFF_V;     // holds bf16 V (ushort) now
  float* aw = ws + OFF_AW;    // becomes probs after k_softmax
  float* ao = ws + OFF_AO;
  float* initacc = ws + OFF_END;
  int* evict = (int*)(ws + OFF_END + (size_t)BHN * 256);

  dim3 gproj(16, 32);
  k_proj<<<gproj, 256, 0, stream>>>(hs, Wq, bq, q, 0.125f, 1);
  k_proj<<<gproj, 256, 0, stream>>>(hs, Wk, bk, k, 1.0f, 1);
  k_proj<<<gproj, 256, 0, stream>>>(hs, Wv, bv, v, 1.0f, 2);   // bf16 head-split

  dim3 gqk(16, 16, BHN);
  k_qk<<<gqk, 256, 0, stream>>>(q, k, aw);

  dim3 grs(TT/4, BHN);
  k_softmax<<<grs, 256, 0, stream>>>(aw);

  k_init_acc<<<BHN, 256, 0, stream>>>(aw, initacc);

  k_scan<<<BHN, 128, 0, stream>>>(aw, initacc, evict);

  dim3 gpv(16, BHN);
  k_pv<<<gpv, 256, 0, stream>>>(aw, evict, (const ushort*)v, ao);

  k_proj<<<gproj, 256, 0, stream>>>(ao, Wo, bo, out, 1.0f, 0);
}

// Round 10
// 660.830 us; speedup vs baseline: 2.1611x; 1.4006x over previous
//
#include <hip/hip_runtime.h>
#include <hip/hip_bf16.h>
#include <stdint.h>

#define TT 1024
#define EE 1024
#define HH 16
#define DD 64
#define BHN 32
#define HB 153
#define RECW 102
#define RING 8
#define INFLT 4
#define NEGF (-3.4028234663852886e38f)

typedef unsigned long long ull;
typedef __attribute__((ext_vector_type(8))) short bf16x8;
typedef __attribute__((ext_vector_type(4))) float f32x4;

// workspace layout (float element offsets)
#define OFF_Q  ((size_t)0)
#define OFF_K  (OFF_Q + (size_t)BHN*TT*DD)
#define OFF_V  (OFF_K + (size_t)BHN*TT*DD)   // reused as bf16 (ushort) buffer
#define OFF_AW (OFF_V + (size_t)BHN*TT*DD)
#define OFF_M  (OFF_AW + (size_t)BHN*TT*TT)
#define OFF_S  (OFF_M + (size_t)BHN*TT)
#define OFF_AO (OFF_S + (size_t)BHN*TT)
#define OFF_END (OFF_AO + (size_t)BHN*TT*DD)
// after OFF_END: initacc float[BHN*256], evict int[BHN*1024]

__device__ __forceinline__ ushort f2bf(float x) {
  unsigned u = __float_as_uint(x);
  u = (u + 0x7FFF + ((u >> 16) & 1)) >> 16;   // RNE
  return (ushort)u;
}
__device__ __forceinline__ float bf2f(ushort h) {
  return __uint_as_float((unsigned)h << 16);
}

// ---------------- split-bf16 MFMA GEMM: Y = (X @ W + b) * scale
// mode: 0 = flat f32, 1 = headsplit f32, 2 = headsplit bf16
// Fragment/epilogue mapping identical to k_pv (HW-verified round 9).
__global__ __launch_bounds__(256) void k_pmm(const float* __restrict__ X,
    const float* __restrict__ W, const float* __restrict__ bias,
    float* __restrict__ Y, float scale, int mode) {
  __shared__ ushort Ah[64][72], Al[64][72];   // X tile hi/lo: [row][k]
  __shared__ ushort Bh[64][72], Bl[64][72];   // W tile hi/lo TRANSPOSED: [col][k]
  int tid = threadIdx.x, lane = tid & 63, wid = tid >> 6;
  int r = tid >> 2, c0 = (tid & 3) * 16;
  int r0 = blockIdx.y * 64, n0 = blockIdx.x * 64;

  f32x4 acc[4];
  #pragma unroll
  for (int nc = 0; nc < 4; ++nc) acc[nc] = (f32x4){0.f, 0.f, 0.f, 0.f};

  for (int k0 = 0; k0 < EE; k0 += 64) {
    __syncthreads();
    // stage A: X[r0+r][k0+c0 .. +16] -> hi/lo, contiguous
    {
      const float4* xs = (const float4*)(X + (size_t)(r0 + r) * EE + k0 + c0);
      #pragma unroll
      for (int q4 = 0; q4 < 4; ++q4) {
        float4 v = xs[q4];
        float f[4] = {v.x, v.y, v.z, v.w};
        ushort hi[4], lo[4];
        #pragma unroll
        for (int u = 0; u < 4; ++u) {
          hi[u] = f2bf(f[u]);
          lo[u] = f2bf(f[u] - bf2f(hi[u]));
        }
        *(unsigned*)&Ah[r][c0 + q4*4]     = (unsigned)hi[0] | ((unsigned)hi[1] << 16);
        *(unsigned*)&Ah[r][c0 + q4*4 + 2] = (unsigned)hi[2] | ((unsigned)hi[3] << 16);
        *(unsigned*)&Al[r][c0 + q4*4]     = (unsigned)lo[0] | ((unsigned)lo[1] << 16);
        *(unsigned*)&Al[r][c0 + q4*4 + 2] = (unsigned)lo[2] | ((unsigned)lo[3] << 16);
      }
    }
    // stage B transposed: W[k0+r][n0+c0 .. +16] -> Bh[c][r]
    {
      const float4* wsrc = (const float4*)(W + (size_t)(k0 + r) * EE + n0 + c0);
      #pragma unroll
      for (int q4 = 0; q4 < 4; ++q4) {
        float4 v = wsrc[q4];
        float f[4] = {v.x, v.y, v.z, v.w};
        #pragma unroll
        for (int u = 0; u < 4; ++u) {
          ushort hi = f2bf(f[u]);
          ushort lo = f2bf(f[u] - bf2f(hi));
          int c = c0 + q4*4 + u;
          Bh[c][r] = hi;
          Bl[c][r] = lo;
        }
      }
    }
    __syncthreads();
    #pragma unroll
    for (int kb = 0; kb < 2; ++kb) {
      bf16x8 ah = *(const bf16x8*)&Ah[wid*16 + (lane & 15)][kb*32 + (lane >> 4)*8];
      bf16x8 al = *(const bf16x8*)&Al[wid*16 + (lane & 15)][kb*32 + (lane >> 4)*8];
      #pragma unroll
      for (int nc = 0; nc < 4; ++nc) {
        bf16x8 bh_ = *(const bf16x8*)&Bh[nc*16 + (lane & 15)][kb*32 + (lane >> 4)*8];
        bf16x8 bl_ = *(const bf16x8*)&Bl[nc*16 + (lane & 15)][kb*32 + (lane >> 4)*8];
        acc[nc] = __builtin_amdgcn_mfma_f32_16x16x32_bf16(ah, bh_, acc[nc], 0, 0, 0);
        acc[nc] = __builtin_amdgcn_mfma_f32_16x16x32_bf16(al, bh_, acc[nc], 0, 0, 0);
        acc[nc] = __builtin_amdgcn_mfma_f32_16x16x32_bf16(ah, bl_, acc[nc], 0, 0, 0);
      }
    }
  }

  int rowbase = wid*16 + (lane >> 4)*4;
  #pragma unroll
  for (int nc = 0; nc < 4; ++nc) {
    int c = n0 + nc*16 + (lane & 15);
    float bv = bias[c];
    #pragma unroll
    for (int qq = 0; qq < 4; ++qq) {
      int rr = r0 + rowbase + qq;
      float val = (acc[nc][qq] + bv) * scale;
      int b_ = rr >> 10, t_ = rr & 1023, h_ = c >> 6, d_ = c & 63;
      if (mode == 1) {
        Y[(((size_t)(b_*HH + h_) * TT) + t_) * DD + d_] = val;
      } else if (mode == 2) {
        ((ushort*)Y)[(((size_t)(b_*HH + h_) * TT) + t_) * DD + d_] = f2bf(val);
      } else {
        Y[(size_t)rr * EE + c] = val;
      }
    }
  }
}

// ---------------- batched QK^T via split-bf16 MFMA (lower-triangle tiles)
__global__ __launch_bounds__(256) void k_qk_mfma(const float* __restrict__ q,
    const float* __restrict__ k, float* __restrict__ aw) {
  int bh = blockIdx.y, tt = blockIdx.x;
  int t0 = tt * 64;
  int tid = threadIdx.x, lane = tid & 63, wid = tid >> 6;
  int r = tid >> 2, c0 = (tid & 3) * 16;
  __shared__ ushort Qh[64][72], Ql[64][72];
  __shared__ ushort Kh[64][72], Kl[64][72];
  const float* qb = q + (size_t)bh * TT * DD;
  const float* kb = k + (size_t)bh * TT * DD;
  float* awb = aw + (size_t)bh * TT * TT;

  // stage Q tile once: q[t0+r][c0..c0+16]
  {
    const float4* xs = (const float4*)(qb + (size_t)(t0 + r) * DD + c0);
    #pragma unroll
    for (int q4 = 0; q4 < 4; ++q4) {
      float4 v = xs[q4];
      float f[4] = {v.x, v.y, v.z, v.w};
      ushort hi[4], lo[4];
      #pragma unroll
      for (int u = 0; u < 4; ++u) {
        hi[u] = f2bf(f[u]);
        lo[u] = f2bf(f[u] - bf2f(hi[u]));
      }
      *(unsigned*)&Qh[r][c0 + q4*4]     = (unsigned)hi[0] | ((unsigned)hi[1] << 16);
      *(unsigned*)&Qh[r][c0 + q4*4 + 2] = (unsigned)hi[2] | ((unsigned)hi[3] << 16);
      *(unsigned*)&Ql[r][c0 + q4*4]     = (unsigned)lo[0] | ((unsigned)lo[1] << 16);
      *(unsigned*)&Ql[r][c0 + q4*4 + 2] = (unsigned)lo[2] | ((unsigned)lo[3] << 16);
    }
  }

  for (int st = 0; st <= tt; ++st) {
    __syncthreads();
    // stage K tile: k[st*64+r][c0..+16] (B-frag[col][k] = K[s][d] directly)
    {
      const float4* xs = (const float4*)(kb + (size_t)(st * 64 + r) * DD + c0);
      #pragma unroll
      for (int q4 = 0; q4 < 4; ++q4) {
        float4 v = xs[q4];
        float f[4] = {v.x, v.y, v.z, v.w};
        ushort hi[4], lo[4];
        #pragma unroll
        for (int u = 0; u < 4; ++u) {
          hi[u] = f2bf(f[u]);
          lo[u] = f2bf(f[u] - bf2f(hi[u]));
        }
        *(unsigned*)&Kh[r][c0 + q4*4]     = (unsigned)hi[0] | ((unsigned)hi[1] << 16);
        *(unsigned*)&Kh[r][c0 + q4*4 + 2] = (unsigned)hi[2] | ((unsigned)hi[3] << 16);
        *(unsigned*)&Kl[r][c0 + q4*4]     = (unsigned)lo[0] | ((unsigned)lo[1] << 16);
        *(unsigned*)&Kl[r][c0 + q4*4 + 2] = (unsigned)lo[2] | ((unsigned)lo[3] << 16);
      }
    }
    __syncthreads();
    f32x4 acc[4];
    #pragma unroll
    for (int nc = 0; nc < 4; ++nc) acc[nc] = (f32x4){0.f, 0.f, 0.f, 0.f};
    #pragma unroll
    for (int kb2 = 0; kb2 < 2; ++kb2) {
      bf16x8 ah = *(const bf16x8*)&Qh[wid*16 + (lane & 15)][kb2*32 + (lane >> 4)*8];
      bf16x8 al = *(const bf16x8*)&Ql[wid*16 + (lane & 15)][kb2*32 + (lane >> 4)*8];
      #pragma unroll
      for (int nc = 0; nc < 4; ++nc) {
        bf16x8 bh_ = *(const bf16x8*)&Kh[nc*16 + (lane & 15)][kb2*32 + (lane >> 4)*8];
        bf16x8 bl_ = *(const bf16x8*)&Kl[nc*16 + (lane & 15)][kb2*32 + (lane >> 4)*8];
        acc[nc] = __builtin_amdgcn_mfma_f32_16x16x32_bf16(ah, bh_, acc[nc], 0, 0, 0);
        acc[nc] = __builtin_amdgcn_mfma_f32_16x16x32_bf16(al, bh_, acc[nc], 0, 0, 0);
        acc[nc] = __builtin_amdgcn_mfma_f32_16x16x32_bf16(ah, bl_, acc[nc], 0, 0, 0);
      }
    }
    int rowbase = wid*16 + (lane >> 4)*4;
    #pragma unroll
    for (int nc = 0; nc < 4; ++nc) {
      int s = st * 64 + nc*16 + (lane & 15);
      #pragma unroll
      for (int qq = 0; qq < 4; ++qq) {
        int t_ = t0 + rowbase + qq;
        awb[(size_t)t_ * TT + s] = acc[nc][qq];
      }
    }
  }
}

// ---------------- row softmax in place: aw row -> probs (lower triangle only)
__global__ __launch_bounds__(256) void k_softmax(float* __restrict__ aw) {
  int bh = blockIdx.y;
  int wid = threadIdx.x >> 6, lane = threadIdx.x & 63;
  int t = blockIdx.x * 4 + wid;
  float* row = aw + ((size_t)bh * TT + t) * TT;
  float vals[16];
  float m = NEGF;
  #pragma unroll
  for (int i = 0; i < 16; ++i) {
    int j = lane + 64*i;
    vals[i] = (j <= t) ? row[j] : NEGF;
    m = fmaxf(m, vals[i]);
  }
  for (int o = 32; o; o >>= 1) m = fmaxf(m, __shfl_xor(m, o));
  float s = 0.f;
  #pragma unroll
  for (int i = 0; i < 16; ++i) {
    int j = lane + 64*i;
    if (j <= t) { vals[i] = expf(vals[i] - m); s += vals[i]; }
  }
  for (int o = 32; o; o >>= 1) s += __shfl_xor(s, o);
  float inv = 1.0f / s;
  #pragma unroll
  for (int i = 0; i < 16; ++i) {
    int j = lane + 64*i;
    if (j <= t) row[j] = vals[i] * inv;
  }
}

// ---------------- parallel init of heavy-hitter scores (p = probs)
__global__ __launch_bounds__(256) void k_init_acc(const float* __restrict__ p,
    float* __restrict__ initacc) {
  int bh = blockIdx.x;
  int c = threadIdx.x;
  float val = 0.f;
  if (c < HB) {
    const float* pb = p + (size_t)bh * TT * TT;
    for (int i = c; i < HB; ++i)
      val += pb[(size_t)i * TT + c];
  }
  initacc[(size_t)bh * 256 + c] = val;
}

// ---------------- wave-wide min over u32 via DPP (VALU path, no LDS)
#define DPP_HOP(ctrl)                                                        \
  {                                                                          \
    unsigned tt = (unsigned)__builtin_amdgcn_update_dpp(                     \
        (int)0xFFFFFFFFu, (int)x, (ctrl), 0xF, 0xF, false);                  \
    x = x < tt ? x : tt;                                                     \
  }
__device__ __forceinline__ unsigned wave_min_u32(unsigned x) {
  DPP_HOP(0x111)  // row_shr:1
  DPP_HOP(0x112)  // row_shr:2
  DPP_HOP(0x114)  // row_shr:4
  DPP_HOP(0x118)  // row_shr:8
  DPP_HOP(0x142)  // row_bcast:15
  DPP_HOP(0x143)  // row_bcast:31
  return (unsigned)__builtin_amdgcn_readlane((int)x, 63);
}

// global -> LDS direct DMA, 16B per lane
__device__ __forceinline__ void gload_lds16(const float* gsrc, float* ldst) {
  __builtin_amdgcn_global_load_lds(
      (const __attribute__((address_space(1))) unsigned int*)gsrc,
      (__attribute__((address_space(3))) unsigned int*)ldst,
      16, 0, 0);
}

// ---------------- serial heavy-hitter scan: DMA producer wave + consumer wave
__global__ __launch_bounds__(128) void k_scan(const float* __restrict__ p,
    const float* __restrict__ initacc, int* __restrict__ evict_g) {
  int bh = blockIdx.x;
  int tid = threadIdx.x;
  int lane = tid & 63;
  const float* pb = p + (size_t)bh * TT * TT;
  __shared__ float ring[RING][TT];
  __shared__ int ev[TT];
  __shared__ volatile int rdyf[RING];
  __shared__ volatile int donef;
  for (int i = tid; i < TT; i += 128) ev[i] = 0x7fffffff;
  if (tid < RING) rdyf[tid] = -1;
  if (tid == 0) donef = -1;
  __syncthreads();

  if (tid >= 64) {
    // ---------- producer: pure DMA via global_load_lds, counted vmcnt ----------
    #pragma unroll
    for (int r = 0; r < INFLT; ++r) {
      const float* srcrow = pb + (size_t)(HB + r) * TT;
      float* slotbase = ring[(HB + r) & (RING - 1)];
      #pragma unroll
      for (int j = 0; j < 4; ++j)
        gload_lds16(srcrow + j * 256 + lane * 4, slotbase + j * 256);
    }
    for (int r = HB; r < TT; ++r) {
      asm volatile("s_waitcnt vmcnt(12)" ::: "memory");
      if (lane == 0) rdyf[r & (RING - 1)] = r;
      int rn = r + INFLT;
      if (rn - RING >= HB) {
        while (donef < rn - RING) { }
      }
      int rsrc = rn < TT ? rn : TT - 1;
      const float* srcrow = pb + (size_t)rsrc * TT;
      float* slotbase = ring[rn & (RING - 1)];
      #pragma unroll
      for (int j = 0; j < 4; ++j)
        gload_lds16(srcrow + j * 256 + lane * 4, slotbase + j * 256);
    }
  } else {
    // ---------- consumer: serial scan, LDS-only critical path ----------
    bool act2 = lane < (HB - 128);   // lane < 25
    int col[3]; float sc[3];
    col[0] = lane;
    col[1] = 64 + lane;
    col[2] = act2 ? (128 + lane) : 0;
    sc[0] = initacc[(size_t)bh * 256 + lane];
    sc[1] = initacc[(size_t)bh * 256 + 64 + lane];
    sc[2] = act2 ? initacc[(size_t)bh * 256 + 128 + lane] : 0.f;
    int fpeek = -2;
    for (int t = HB; t < TT; ++t) {
      int slot = t & (RING - 1);
      if (fpeek != t) {
        while (rdyf[slot] != t) { }
      }
      asm volatile("" ::: "memory");
      const float* rb = ring[slot];
      float r0 = rb[col[0]];
      float r1 = rb[col[1]];
      float r2 = rb[col[2]];
      float rd = rb[t];
      fpeek = rdyf[(t + 1) & (RING - 1)];
      unsigned b0 = __float_as_uint(sc[0]);
      unsigned b1 = __float_as_uint(sc[1]);
      unsigned b2 = act2 ? __float_as_uint(sc[2]) : 0xFFFFFFFFu;
      unsigned mn = b0 < b1 ? b0 : b1; mn = mn < b2 ? mn : b2;
      unsigned mstar = wave_min_u32(mn);
      unsigned c0k = (b0 == mstar) ? (unsigned)(1023 - col[0]) : 0xFFFFFFFFu;
      unsigned c1k = (b1 == mstar) ? (unsigned)(1023 - col[1]) : 0xFFFFFFFFu;
      unsigned c2k = (act2 && b2 == mstar) ? (unsigned)(1023 - col[2]) : 0xFFFFFFFFu;
      unsigned cm = c0k < c1k ? c0k : c1k; cm = cm < c2k ? cm : c2k;
      int cstar = 1023 - (int)wave_min_u32(cm);
      if (b0 == mstar && col[0] == cstar) { ev[col[0]] = t; col[0] = t; sc[0] = rd; }
      else sc[0] += r0;
      if (b1 == mstar && col[1] == cstar) { ev[col[1]] = t; col[1] = t; sc[1] = rd; }
      else sc[1] += r1;
      if (act2) {
        if (b2 == mstar && col[2] == cstar) { ev[col[2]] = t; col[2] = t; sc[2] = rd; }
        else sc[2] += r2;
      }
      asm volatile("" ::: "memory");
      if (lane == 0) donef = t;
    }
  }

  __syncthreads();
  int4* dst4 = (int4*)(evict_g + (size_t)bh * TT);
  const int4* src4 = (const int4*)ev;
  for (int i = tid; i < TT/4; i += 128) dst4[i] = src4[i];
}

// ---------------- fused mask + renorm + PV via bf16 MFMA
__global__ __launch_bounds__(256) void k_pv(const float* __restrict__ p,
    const int* __restrict__ evict_g, const ushort* __restrict__ vbf,
    float* __restrict__ ao) {
  int bh = blockIdx.y, tt = blockIdx.x;
  int tid = threadIdx.x, lane = tid & 63, wid = tid >> 6;
  int t0 = tt * 64;
  __shared__ ushort PA[64][72];   // masked bf16 P tile
  __shared__ ushort VT[64][72];   // V tile transposed: VT[d][s]
  __shared__ float rowsum[64];
  __shared__ int et[TT];
  ((int4*)et)[tid] = ((const int4*)(evict_g + (size_t)bh * TT))[tid];
  if (tid < 64) rowsum[tid] = 0.f;
  const float* pb = p + ((size_t)bh * TT + t0) * TT;
  const ushort* vb = vbf + (size_t)bh * TT * DD;

  f32x4 acc[4];
  #pragma unroll
  for (int nc = 0; nc < 4; ++nc) acc[nc] = (f32x4){0.f, 0.f, 0.f, 0.f};

  int r = tid >> 2;
  int c0 = (tid & 3) * 16;
  int tg = t0 + r;
  __syncthreads();

  for (int st = 0; st <= tt; ++st) {
    const float* prow = pb + (size_t)r * TT + st * 64 + c0;
    float part = 0.f;
    ushort tmp16[16];
    #pragma unroll
    for (int q4 = 0; q4 < 4; ++q4) {
      float4 pv4 = *(const float4*)(prow + q4 * 4);
      float vals[4] = {pv4.x, pv4.y, pv4.z, pv4.w};
      #pragma unroll
      for (int u = 0; u < 4; ++u) {
        int j = st * 64 + c0 + q4 * 4 + u;
        bool allow = (j <= tg) && ((et[j] > tg) || (j + RECW >= tg));
        float mv = allow ? vals[u] : 0.f;
        part += mv;
        tmp16[q4 * 4 + u] = f2bf(mv);
      }
    }
    #pragma unroll
    for (int w2 = 0; w2 < 8; ++w2) {
      unsigned pk = (unsigned)tmp16[w2 * 2] | ((unsigned)tmp16[w2 * 2 + 1] << 16);
      *(unsigned*)&PA[r][c0 + w2 * 2] = pk;
    }
    part += __shfl_xor(part, 1);
    part += __shfl_xor(part, 2);
    if ((tid & 3) == 0) rowsum[r] += part;
    {
      const unsigned* vrow32 = (const unsigned*)(vb + (size_t)(st * 64 + r) * DD + c0);
      #pragma unroll
      for (int u = 0; u < 8; ++u) {
        unsigned vv = vrow32[u];
        VT[c0 + u * 2][r] = (ushort)(vv & 0xFFFF);
        VT[c0 + u * 2 + 1][r] = (ushort)(vv >> 16);
      }
    }
    __syncthreads();
    #pragma unroll
    for (int kb = 0; kb < 2; ++kb) {
      bf16x8 af = *(const bf16x8*)&PA[wid * 16 + (lane & 15)][kb * 32 + (lane >> 4) * 8];
      #pragma unroll
      for (int nc = 0; nc < 4; ++nc) {
        bf16x8 bfr = *(const bf16x8*)&VT[nc * 16 + (lane & 15)][kb * 32 + (lane >> 4) * 8];
        acc[nc] = __builtin_amdgcn_mfma_f32_16x16x32_bf16(af, bfr, acc[nc], 0, 0, 0);
      }
    }
    __syncthreads();
  }

  int b_ = bh >> 4, h_ = bh & 15;
  int rl = wid * 16 + (lane >> 4) * 4;
  #pragma unroll
  for (int nc = 0; nc < 4; ++nc) {
    int d = nc * 16 + (lane & 15);
    #pragma unroll
    for (int qq = 0; qq < 4; ++qq) {
      int rr = rl + qq;
      float outv = acc[nc][qq] / rowsum[rr];
      ao[((size_t)b_ * TT + (t0 + rr)) * EE + h_ * DD + d] = outv;
    }
  }
}

extern "C" void kernel_launch(void* const* d_in, const int* in_sizes, int n_in,
                              void* d_out, int out_size, void* d_ws, size_t ws_size,
                              hipStream_t stream) {
  const float* hs = (const float*)d_in[0];
  const float* Wq = (const float*)d_in[2];
  const float* bq = (const float*)d_in[3];
  const float* Wk = (const float*)d_in[4];
  const float* bk = (const float*)d_in[5];
  const float* Wv = (const float*)d_in[6];
  const float* bv = (const float*)d_in[7];
  const float* Wo = (const float*)d_in[8];
  const float* bo = (const float*)d_in[9];
  float* out = (float*)d_out;

  float* ws = (float*)d_ws;
  float* q  = ws + OFF_Q;
  float* k  = ws + OFF_K;
  float* v  = ws + OFF_V;     // holds bf16 V (ushort)
  float* aw = ws + OFF_AW;    // becomes probs after k_softmax
  float* ao = ws + OFF_AO;
  float* initacc = ws + OFF_END;
  int* evict = (int*)(ws + OFF_END + (size_t)BHN * 256);

  dim3 gproj(16, 32);
  k_pmm<<<gproj, 256, 0, stream>>>(hs, Wq, bq, q, 0.125f, 1);
  k_pmm<<<gproj, 256, 0, stream>>>(hs, Wk, bk, k, 1.0f, 1);
  k_pmm<<<gproj, 256, 0, stream>>>(hs, Wv, bv, v, 1.0f, 2);   // bf16 head-split

  dim3 gqk(16, BHN);
  k_qk_mfma<<<gqk, 256, 0, stream>>>(q, k, aw);

  dim3 grs(TT/4, BHN);
  k_softmax<<<grs, 256, 0, stream>>>(aw);

  k_init_acc<<<BHN, 256, 0, stream>>>(aw, initacc);

  k_scan<<<BHN, 128, 0, stream>>>(aw, initacc, evict);

  dim3 gpv(16, BHN);
  k_pv<<<gpv, 256, 0, stream>>>(aw, evict, (const ushort*)v, ao);

  k_pmm<<<gproj, 256, 0, stream>>>(ao, Wo, bo, out, 1.0f, 0);
}

// Round 11
// 632.094 us; speedup vs baseline: 2.2593x; 1.0455x over previous
//
#include <hip/hip_runtime.h>
#include <hip/hip_bf16.h>
#include <stdint.h>

#define TT 1024
#define EE 1024
#define HH 16
#define DD 64
#define BHN 32
#define HB 153
#define RECW 102
#define RING 16
#define INFLT 8
#define NEGF (-3.4028234663852886e38f)

typedef unsigned long long ull;
typedef __attribute__((ext_vector_type(8))) short bf16x8;
typedef __attribute__((ext_vector_type(4))) float f32x4;

// workspace layout (float element offsets)
#define OFF_Q  ((size_t)0)
#define OFF_K  (OFF_Q + (size_t)BHN*TT*DD)
#define OFF_V  (OFF_K + (size_t)BHN*TT*DD)   // reused as bf16 (ushort) buffer
#define OFF_AW (OFF_V + (size_t)BHN*TT*DD)
#define OFF_M  (OFF_AW + (size_t)BHN*TT*TT)
#define OFF_S  (OFF_M + (size_t)BHN*TT)
#define OFF_AO (OFF_S + (size_t)BHN*TT)
#define OFF_END (OFF_AO + (size_t)BHN*TT*DD)
// after OFF_END: initacc float[BHN*256], evict int[BHN*1024]

__device__ __forceinline__ ushort f2bf(float x) {
  unsigned u = __float_as_uint(x);
  u = (u + 0x7FFF + ((u >> 16) & 1)) >> 16;   // RNE
  return (ushort)u;
}
__device__ __forceinline__ float bf2f(ushort h) {
  return __uint_as_float((unsigned)h << 16);
}

// ---------------- split-bf16 MFMA GEMM: Y = (X @ W + b) * scale
// mode: 0 = flat f32, 1 = headsplit f32, 2 = headsplit bf16
__global__ __launch_bounds__(256) void k_pmm(const float* __restrict__ X,
    const float* __restrict__ W, const float* __restrict__ bias,
    float* __restrict__ Y, float scale, int mode) {
  __shared__ ushort Ah[64][72], Al[64][72];   // X tile hi/lo: [row][k]
  __shared__ ushort Bh[64][72], Bl[64][72];   // W tile hi/lo TRANSPOSED: [col][k]
  int tid = threadIdx.x, lane = tid & 63, wid = tid >> 6;
  int r = tid >> 2, c0 = (tid & 3) * 16;
  int r0 = blockIdx.y * 64, n0 = blockIdx.x * 64;

  f32x4 acc[4];
  #pragma unroll
  for (int nc = 0; nc < 4; ++nc) acc[nc] = (f32x4){0.f, 0.f, 0.f, 0.f};

  for (int k0 = 0; k0 < EE; k0 += 64) {
    __syncthreads();
    {
      const float4* xs = (const float4*)(X + (size_t)(r0 + r) * EE + k0 + c0);
      #pragma unroll
      for (int q4 = 0; q4 < 4; ++q4) {
        float4 v = xs[q4];
        float f[4] = {v.x, v.y, v.z, v.w};
        ushort hi[4], lo[4];
        #pragma unroll
        for (int u = 0; u < 4; ++u) {
          hi[u] = f2bf(f[u]);
          lo[u] = f2bf(f[u] - bf2f(hi[u]));
        }
        *(unsigned*)&Ah[r][c0 + q4*4]     = (unsigned)hi[0] | ((unsigned)hi[1] << 16);
        *(unsigned*)&Ah[r][c0 + q4*4 + 2] = (unsigned)hi[2] | ((unsigned)hi[3] << 16);
        *(unsigned*)&Al[r][c0 + q4*4]     = (unsigned)lo[0] | ((unsigned)lo[1] << 16);
        *(unsigned*)&Al[r][c0 + q4*4 + 2] = (unsigned)lo[2] | ((unsigned)lo[3] << 16);
      }
    }
    {
      const float4* wsrc = (const float4*)(W + (size_t)(k0 + r) * EE + n0 + c0);
      #pragma unroll
      for (int q4 = 0; q4 < 4; ++q4) {
        float4 v = wsrc[q4];
        float f[4] = {v.x, v.y, v.z, v.w};
        #pragma unroll
        for (int u = 0; u < 4; ++u) {
          ushort hi = f2bf(f[u]);
          ushort lo = f2bf(f[u] - bf2f(hi));
          int c = c0 + q4*4 + u;
          Bh[c][r] = hi;
          Bl[c][r] = lo;
        }
      }
    }
    __syncthreads();
    #pragma unroll
    for (int kb = 0; kb < 2; ++kb) {
      bf16x8 ah = *(const bf16x8*)&Ah[wid*16 + (lane & 15)][kb*32 + (lane >> 4)*8];
      bf16x8 al = *(const bf16x8*)&Al[wid*16 + (lane & 15)][kb*32 + (lane >> 4)*8];
      #pragma unroll
      for (int nc = 0; nc < 4; ++nc) {
        bf16x8 bh_ = *(const bf16x8*)&Bh[nc*16 + (lane & 15)][kb*32 + (lane >> 4)*8];
        bf16x8 bl_ = *(const bf16x8*)&Bl[nc*16 + (lane & 15)][kb*32 + (lane >> 4)*8];
        acc[nc] = __builtin_amdgcn_mfma_f32_16x16x32_bf16(ah, bh_, acc[nc], 0, 0, 0);
        acc[nc] = __builtin_amdgcn_mfma_f32_16x16x32_bf16(al, bh_, acc[nc], 0, 0, 0);
        acc[nc] = __builtin_amdgcn_mfma_f32_16x16x32_bf16(ah, bl_, acc[nc], 0, 0, 0);
      }
    }
  }

  int rowbase = wid*16 + (lane >> 4)*4;
  #pragma unroll
  for (int nc = 0; nc < 4; ++nc) {
    int c = n0 + nc*16 + (lane & 15);
    float bv = bias[c];
    #pragma unroll
    for (int qq = 0; qq < 4; ++qq) {
      int rr = r0 + rowbase + qq;
      float val = (acc[nc][qq] + bv) * scale;
      int b_ = rr >> 10, t_ = rr & 1023, h_ = c >> 6, d_ = c & 63;
      if (mode == 1) {
        Y[(((size_t)(b_*HH + h_) * TT) + t_) * DD + d_] = val;
      } else if (mode == 2) {
        ((ushort*)Y)[(((size_t)(b_*HH + h_) * TT) + t_) * DD + d_] = f2bf(val);
      } else {
        Y[(size_t)rr * EE + c] = val;
      }
    }
  }
}

// ---------------- batched QK^T via split-bf16 MFMA (lower-triangle tiles)
__global__ __launch_bounds__(256) void k_qk_mfma(const float* __restrict__ q,
    const float* __restrict__ k, float* __restrict__ aw) {
  int bh = blockIdx.y, tt = blockIdx.x;
  int t0 = tt * 64;
  int tid = threadIdx.x, lane = tid & 63, wid = tid >> 6;
  int r = tid >> 2, c0 = (tid & 3) * 16;
  __shared__ ushort Qh[64][72], Ql[64][72];
  __shared__ ushort Kh[64][72], Kl[64][72];
  const float* qb = q + (size_t)bh * TT * DD;
  const float* kb = k + (size_t)bh * TT * DD;
  float* awb = aw + (size_t)bh * TT * TT;

  {
    const float4* xs = (const float4*)(qb + (size_t)(t0 + r) * DD + c0);
    #pragma unroll
    for (int q4 = 0; q4 < 4; ++q4) {
      float4 v = xs[q4];
      float f[4] = {v.x, v.y, v.z, v.w};
      ushort hi[4], lo[4];
      #pragma unroll
      for (int u = 0; u < 4; ++u) {
        hi[u] = f2bf(f[u]);
        lo[u] = f2bf(f[u] - bf2f(hi[u]));
      }
      *(unsigned*)&Qh[r][c0 + q4*4]     = (unsigned)hi[0] | ((unsigned)hi[1] << 16);
      *(unsigned*)&Qh[r][c0 + q4*4 + 2] = (unsigned)hi[2] | ((unsigned)hi[3] << 16);
      *(unsigned*)&Ql[r][c0 + q4*4]     = (unsigned)lo[0] | ((unsigned)lo[1] << 16);
      *(unsigned*)&Ql[r][c0 + q4*4 + 2] = (unsigned)lo[2] | ((unsigned)lo[3] << 16);
    }
  }

  for (int st = 0; st <= tt; ++st) {
    __syncthreads();
    {
      const float4* xs = (const float4*)(kb + (size_t)(st * 64 + r) * DD + c0);
      #pragma unroll
      for (int q4 = 0; q4 < 4; ++q4) {
        float4 v = xs[q4];
        float f[4] = {v.x, v.y, v.z, v.w};
        ushort hi[4], lo[4];
        #pragma unroll
        for (int u = 0; u < 4; ++u) {
          hi[u] = f2bf(f[u]);
          lo[u] = f2bf(f[u] - bf2f(hi[u]));
        }
        *(unsigned*)&Kh[r][c0 + q4*4]     = (unsigned)hi[0] | ((unsigned)hi[1] << 16);
        *(unsigned*)&Kh[r][c0 + q4*4 + 2] = (unsigned)hi[2] | ((unsigned)hi[3] << 16);
        *(unsigned*)&Kl[r][c0 + q4*4]     = (unsigned)lo[0] | ((unsigned)lo[1] << 16);
        *(unsigned*)&Kl[r][c0 + q4*4 + 2] = (unsigned)lo[2] | ((unsigned)lo[3] << 16);
      }
    }
    __syncthreads();
    f32x4 acc[4];
    #pragma unroll
    for (int nc = 0; nc < 4; ++nc) acc[nc] = (f32x4){0.f, 0.f, 0.f, 0.f};
    #pragma unroll
    for (int kb2 = 0; kb2 < 2; ++kb2) {
      bf16x8 ah = *(const bf16x8*)&Qh[wid*16 + (lane & 15)][kb2*32 + (lane >> 4)*8];
      bf16x8 al = *(const bf16x8*)&Ql[wid*16 + (lane & 15)][kb2*32 + (lane >> 4)*8];
      #pragma unroll
      for (int nc = 0; nc < 4; ++nc) {
        bf16x8 bh_ = *(const bf16x8*)&Kh[nc*16 + (lane & 15)][kb2*32 + (lane >> 4)*8];
        bf16x8 bl_ = *(const bf16x8*)&Kl[nc*16 + (lane & 15)][kb2*32 + (lane >> 4)*8];
        acc[nc] = __builtin_amdgcn_mfma_f32_16x16x32_bf16(ah, bh_, acc[nc], 0, 0, 0);
        acc[nc] = __builtin_amdgcn_mfma_f32_16x16x32_bf16(al, bh_, acc[nc], 0, 0, 0);
        acc[nc] = __builtin_amdgcn_mfma_f32_16x16x32_bf16(ah, bl_, acc[nc], 0, 0, 0);
      }
    }
    int rowbase = wid*16 + (lane >> 4)*4;
    #pragma unroll
    for (int nc = 0; nc < 4; ++nc) {
      int s = st * 64 + nc*16 + (lane & 15);
      #pragma unroll
      for (int qq = 0; qq < 4; ++qq) {
        int t_ = t0 + rowbase + qq;
        awb[(size_t)t_ * TT + s] = acc[nc][qq];
      }
    }
  }
}

// ---------------- row softmax in place: aw row -> probs (lower triangle only)
__global__ __launch_bounds__(256) void k_softmax(float* __restrict__ aw) {
  int bh = blockIdx.y;
  int wid = threadIdx.x >> 6, lane = threadIdx.x & 63;
  int t = blockIdx.x * 4 + wid;
  float* row = aw + ((size_t)bh * TT + t) * TT;
  float vals[16];
  float m = NEGF;
  #pragma unroll
  for (int i = 0; i < 16; ++i) {
    int j = lane + 64*i;
    vals[i] = (j <= t) ? row[j] : NEGF;
    m = fmaxf(m, vals[i]);
  }
  for (int o = 32; o; o >>= 1) m = fmaxf(m, __shfl_xor(m, o));
  float s = 0.f;
  #pragma unroll
  for (int i = 0; i < 16; ++i) {
    int j = lane + 64*i;
    if (j <= t) { vals[i] = expf(vals[i] - m); s += vals[i]; }
  }
  for (int o = 32; o; o >>= 1) s += __shfl_xor(s, o);
  float inv = 1.0f / s;
  #pragma unroll
  for (int i = 0; i < 16; ++i) {
    int j = lane + 64*i;
    if (j <= t) row[j] = vals[i] * inv;
  }
}

// ---------------- parallel init of heavy-hitter scores (p = probs)
__global__ __launch_bounds__(256) void k_init_acc(const float* __restrict__ p,
    float* __restrict__ initacc) {
  int bh = blockIdx.x;
  int c = threadIdx.x;
  float val = 0.f;
  if (c < HB) {
    const float* pb = p + (size_t)bh * TT * TT;
    for (int i = c; i < HB; ++i)
      val += pb[(size_t)i * TT + c];
  }
  initacc[(size_t)bh * 256 + c] = val;
}

// ---------------- wave-wide min over u32 via DPP (VALU path, no LDS)
#define DPP_HOP(ctrl)                                                        \
  {                                                                          \
    unsigned tt = (unsigned)__builtin_amdgcn_update_dpp(                     \
        (int)0xFFFFFFFFu, (int)x, (ctrl), 0xF, 0xF, false);                  \
    x = x < tt ? x : tt;                                                     \
  }
__device__ __forceinline__ unsigned wave_min_u32(unsigned x) {
  DPP_HOP(0x111)  // row_shr:1
  DPP_HOP(0x112)  // row_shr:2
  DPP_HOP(0x114)  // row_shr:4
  DPP_HOP(0x118)  // row_shr:8
  DPP_HOP(0x142)  // row_bcast:15
  DPP_HOP(0x143)  // row_bcast:31
  return (unsigned)__builtin_amdgcn_readlane((int)x, 63);
}

// global -> LDS direct DMA, 16B per lane
__device__ __forceinline__ void gload_lds16(const float* gsrc, float* ldst) {
  __builtin_amdgcn_global_load_lds(
      (const __attribute__((address_space(1))) unsigned int*)gsrc,
      (__attribute__((address_space(3))) unsigned int*)ldst,
      16, 0, 0);
}

// ---------------- serial heavy-hitter scan: DMA producer wave + pipelined consumer
// Producer: RING=16 slots, INFLT=8 rows (32 loads) in flight, vmcnt(28) => oldest
// row landed. Consumer: software-pipelined — select(t) uses cstar computed at the
// TAIL of step t-1, overlapping the DPP reduce with the ds_reads for the next row.
__global__ __launch_bounds__(128) void k_scan(const float* __restrict__ p,
    const float* __restrict__ initacc, int* __restrict__ evict_g) {
  int bh = blockIdx.x;
  int tid = threadIdx.x;
  int lane = tid & 63;
  const float* pb = p + (size_t)bh * TT * TT;
  __shared__ float ring[RING][TT];
  __shared__ int ev[TT];
  __shared__ volatile int rdyf[RING];
  __shared__ volatile int donef;
  for (int i = tid; i < TT; i += 128) ev[i] = 0x7fffffff;
  if (tid < RING) rdyf[tid] = -1;
  if (tid == 0) donef = -1;
  __syncthreads();

  if (tid >= 64) {
    // ---------- producer: pure DMA via global_load_lds, counted vmcnt ----------
    #pragma unroll
    for (int r = 0; r < INFLT; ++r) {
      const float* srcrow = pb + (size_t)(HB + r) * TT;
      float* slotbase = ring[(HB + r) & (RING - 1)];
      #pragma unroll
      for (int j = 0; j < 4; ++j)
        gload_lds16(srcrow + j * 256 + lane * 4, slotbase + j * 256);
    }
    for (int r = HB; r < TT; ++r) {
      asm volatile("s_waitcnt vmcnt(28)" ::: "memory");
      if (lane == 0) rdyf[r & (RING - 1)] = r;
      int rn = r + INFLT;
      if (rn - RING >= HB) {
        while (donef < rn - RING) { }
      }
      int rsrc = rn < TT ? rn : TT - 1;   // tail: garbage refetch into dead slot
      const float* srcrow = pb + (size_t)rsrc * TT;
      float* slotbase = ring[rn & (RING - 1)];
      #pragma unroll
      for (int j = 0; j < 4; ++j)
        gload_lds16(srcrow + j * 256 + lane * 4, slotbase + j * 256);
    }
  } else {
    // ---------- consumer: pipelined serial scan ----------
    bool act2 = lane < (HB - 128);   // lane < 25
    int col0 = lane, col1 = 64 + lane, col2 = act2 ? (128 + lane) : 0;
    float sc0 = initacc[(size_t)bh * 256 + lane];
    float sc1 = initacc[(size_t)bh * 256 + 64 + lane];
    float sc2 = act2 ? initacc[(size_t)bh * 256 + 128 + lane] : 0.f;

    // prologue: wait row HB, read it, compute reduce for t=HB
    while (rdyf[HB & (RING - 1)] != HB) { }
    asm volatile("" ::: "memory");
    int fpeek = rdyf[(HB + 1) & (RING - 1)];
    float r0, r1, r2, rd;
    {
      const float* rb = ring[HB & (RING - 1)];
      r0 = rb[col0]; r1 = rb[col1]; r2 = rb[col2]; rd = rb[HB];
    }
    int cstar;
    {
      unsigned b0 = __float_as_uint(sc0);
      unsigned b1 = __float_as_uint(sc1);
      unsigned b2 = act2 ? __float_as_uint(sc2) : 0xFFFFFFFFu;
      unsigned mn = b0 < b1 ? b0 : b1; mn = mn < b2 ? mn : b2;
      unsigned mstar = wave_min_u32(mn);
      unsigned c0k = (b0 == mstar) ? (unsigned)(1023 - col0) : 0xFFFFFFFFu;
      unsigned c1k = (b1 == mstar) ? (unsigned)(1023 - col1) : 0xFFFFFFFFu;
      unsigned c2k = (act2 && b2 == mstar) ? (unsigned)(1023 - col2) : 0xFFFFFFFFu;
      unsigned cm = c0k < c1k ? c0k : c1k; cm = cm < c2k ? cm : c2k;
      cstar = 1023 - (int)wave_min_u32(cm);
    }

    for (int t = HB; t < TT; ++t) {
      // select for step t (cols are a distinct set -> col==cstar suffices)
      if (col0 == cstar) { ev[col0] = t; col0 = t; sc0 = rd; } else sc0 += r0;
      if (col1 == cstar) { ev[col1] = t; col1 = t; sc1 = rd; } else sc1 += r1;
      if (act2) {
        if (col2 == cstar) { ev[col2] = t; col2 = t; sc2 = rd; } else sc2 += r2;
      }
      if (lane == 0) donef = t;
      if (t + 1 < TT) {
        int slot = (t + 1) & (RING - 1);
        if (fpeek != t + 1) {
          while (rdyf[slot] != t + 1) { }
        }
        asm volatile("" ::: "memory");
        fpeek = rdyf[(t + 2) & (RING - 1)];
        // issue next-row reads (overlap with the reduce below)
        const float* rb = ring[slot];
        r0 = rb[col0]; r1 = rb[col1]; r2 = rb[col2]; rd = rb[t + 1];
        // reduce for t+1 from post-select scores (pure VALU, overlaps ds_reads)
        unsigned b0 = __float_as_uint(sc0);
        unsigned b1 = __float_as_uint(sc1);
        unsigned b2 = act2 ? __float_as_uint(sc2) : 0xFFFFFFFFu;
        unsigned mn = b0 < b1 ? b0 : b1; mn = mn < b2 ? mn : b2;
        unsigned mstar = wave_min_u32(mn);
        unsigned c0k = (b0 == mstar) ? (unsigned)(1023 - col0) : 0xFFFFFFFFu;
        unsigned c1k = (b1 == mstar) ? (unsigned)(1023 - col1) : 0xFFFFFFFFu;
        unsigned c2k = (act2 && b2 == mstar) ? (unsigned)(1023 - col2) : 0xFFFFFFFFu;
        unsigned cm = c0k < c1k ? c0k : c1k; cm = cm < c2k ? cm : c2k;
        cstar = 1023 - (int)wave_min_u32(cm);
      }
    }
  }

  __syncthreads();
  int4* dst4 = (int4*)(evict_g + (size_t)bh * TT);
  const int4* src4 = (const int4*)ev;
  for (int i = tid; i < TT/4; i += 128) dst4[i] = src4[i];
}

// ---------------- fused mask + renorm + PV via bf16 MFMA
__global__ __launch_bounds__(256) void k_pv(const float* __restrict__ p,
    const int* __restrict__ evict_g, const ushort* __restrict__ vbf,
    float* __restrict__ ao) {
  int bh = blockIdx.y, tt = blockIdx.x;
  int tid = threadIdx.x, lane = tid & 63, wid = tid >> 6;
  int t0 = tt * 64;
  __shared__ ushort PA[64][72];   // masked bf16 P tile
  __shared__ ushort VT[64][72];   // V tile transposed: VT[d][s]
  __shared__ float rowsum[64];
  __shared__ int et[TT];
  ((int4*)et)[tid] = ((const int4*)(evict_g + (size_t)bh * TT))[tid];
  if (tid < 64) rowsum[tid] = 0.f;
  const float* pb = p + ((size_t)bh * TT + t0) * TT;
  const ushort* vb = vbf + (size_t)bh * TT * DD;

  f32x4 acc[4];
  #pragma unroll
  for (int nc = 0; nc < 4; ++nc) acc[nc] = (f32x4){0.f, 0.f, 0.f, 0.f};

  int r = tid >> 2;
  int c0 = (tid & 3) * 16;
  int tg = t0 + r;
  __syncthreads();

  for (int st = 0; st <= tt; ++st) {
    const float* prow = pb + (size_t)r * TT + st * 64 + c0;
    float part = 0.f;
    ushort tmp16[16];
    #pragma unroll
    for (int q4 = 0; q4 < 4; ++q4) {
      float4 pv4 = *(const float4*)(prow + q4 * 4);
      float vals[4] = {pv4.x, pv4.y, pv4.z, pv4.w};
      #pragma unroll
      for (int u = 0; u < 4; ++u) {
        int j = st * 64 + c0 + q4 * 4 + u;
        bool allow = (j <= tg) && ((et[j] > tg) || (j + RECW >= tg));
        float mv = allow ? vals[u] : 0.f;
        part += mv;
        tmp16[q4 * 4 + u] = f2bf(mv);
      }
    }
    #pragma unroll
    for (int w2 = 0; w2 < 8; ++w2) {
      unsigned pk = (unsigned)tmp16[w2 * 2] | ((unsigned)tmp16[w2 * 2 + 1] << 16);
      *(unsigned*)&PA[r][c0 + w2 * 2] = pk;
    }
    part += __shfl_xor(part, 1);
    part += __shfl_xor(part, 2);
    if ((tid & 3) == 0) rowsum[r] += part;
    {
      const unsigned* vrow32 = (const unsigned*)(vb + (size_t)(st * 64 + r) * DD + c0);
      #pragma unroll
      for (int u = 0; u < 8; ++u) {
        unsigned vv = vrow32[u];
        VT[c0 + u * 2][r] = (ushort)(vv & 0xFFFF);
        VT[c0 + u * 2 + 1][r] = (ushort)(vv >> 16);
      }
    }
    __syncthreads();
    #pragma unroll
    for (int kb = 0; kb < 2; ++kb) {
      bf16x8 af = *(const bf16x8*)&PA[wid * 16 + (lane & 15)][kb * 32 + (lane >> 4) * 8];
      #pragma unroll
      for (int nc = 0; nc < 4; ++nc) {
        bf16x8 bfr = *(const bf16x8*)&VT[nc * 16 + (lane & 15)][kb * 32 + (lane >> 4) * 8];
        acc[nc] = __builtin_amdgcn_mfma_f32_16x16x32_bf16(af, bfr, acc[nc], 0, 0, 0);
      }
    }
    __syncthreads();
  }

  int b_ = bh >> 4, h_ = bh & 15;
  int rl = wid * 16 + (lane >> 4) * 4;
  #pragma unroll
  for (int nc = 0; nc < 4; ++nc) {
    int d = nc * 16 + (lane & 15);
    #pragma unroll
    for (int qq = 0; qq < 4; ++qq) {
      int rr = rl + qq;
      float outv = acc[nc][qq] / rowsum[rr];
      ao[((size_t)b_ * TT + (t0 + rr)) * EE + h_ * DD + d] = outv;
    }
  }
}

extern "C" void kernel_launch(void* const* d_in, const int* in_sizes, int n_in,
                              void* d_out, int out_size, void* d_ws, size_t ws_size,
                              hipStream_t stream) {
  const float* hs = (const float*)d_in[0];
  const float* Wq = (const float*)d_in[2];
  const float* bq = (const float*)d_in[3];
  const float* Wk = (const float*)d_in[4];
  const float* bk = (const float*)d_in[5];
  const float* Wv = (const float*)d_in[6];
  const float* bv = (const float*)d_in[7];
  const float* Wo = (const float*)d_in[8];
  const float* bo = (const float*)d_in[9];
  float* out = (float*)d_out;

  float* ws = (float*)d_ws;
  float* q  = ws + OFF_Q;
  float* k  = ws + OFF_K;
  float* v  = ws + OFF_V;     // holds bf16 V (ushort)
  float* aw = ws + OFF_AW;    // becomes probs after k_softmax
  float* ao = ws + OFF_AO;
  float* initacc = ws + OFF_END;
  int* evict = (int*)(ws + OFF_END + (size_t)BHN * 256);

  dim3 gproj(16, 32);
  k_pmm<<<gproj, 256, 0, stream>>>(hs, Wq, bq, q, 0.125f, 1);
  k_pmm<<<gproj, 256, 0, stream>>>(hs, Wk, bk, k, 1.0f, 1);
  k_pmm<<<gproj, 256, 0, stream>>>(hs, Wv, bv, v, 1.0f, 2);   // bf16 head-split

  dim3 gqk(16, BHN);
  k_qk_mfma<<<gqk, 256, 0, stream>>>(q, k, aw);

  dim3 grs(TT/4, BHN);
  k_softmax<<<grs, 256, 0, stream>>>(aw);

  k_init_acc<<<BHN, 256, 0, stream>>>(aw, initacc);

  k_scan<<<BHN, 128, 0, stream>>>(aw, initacc, evict);

  dim3 gpv(16, BHN);
  k_pv<<<gpv, 256, 0, stream>>>(aw, evict, (const ushort*)v, ao);

  dim3 gout(16, 32);
  k_pmm<<<gout, 256, 0, stream>>>(ao, Wo, bo, out, 1.0f, 0);
}

// Round 12
// 590.235 us; speedup vs baseline: 2.4195x; 1.0709x over previous
//
#include <hip/hip_runtime.h>
#include <hip/hip_bf16.h>
#include <stdint.h>

#define TT 1024
#define EE 1024
#define HH 16
#define DD 64
#define BHN 32
#define HB 153
#define RECW 102
#define RING 16
#define INFLT 8
#define NEGF (-3.4028234663852886e38f)

typedef unsigned long long ull;
typedef __attribute__((ext_vector_type(8))) short bf16x8;
typedef __attribute__((ext_vector_type(4))) float f32x4;
typedef __attribute__((address_space(3))) float lds_float;

// workspace layout (float element offsets)
#define OFF_Q  ((size_t)0)
#define OFF_K  (OFF_Q + (size_t)BHN*TT*DD)
#define OFF_V  (OFF_K + (size_t)BHN*TT*DD)   // reused as bf16 (ushort) buffer
#define OFF_AW (OFF_V + (size_t)BHN*TT*DD)
#define OFF_M  (OFF_AW + (size_t)BHN*TT*TT)
#define OFF_S  (OFF_M + (size_t)BHN*TT)
#define OFF_AO (OFF_S + (size_t)BHN*TT)
#define OFF_END (OFF_AO + (size_t)BHN*TT*DD)
// after OFF_END: initacc float[BHN*256], evict int[BHN*1024]

__device__ __forceinline__ ushort f2bf(float x) {
  unsigned u = __float_as_uint(x);
  u = (u + 0x7FFF + ((u >> 16) & 1)) >> 16;   // RNE
  return (ushort)u;
}
__device__ __forceinline__ float bf2f(ushort h) {
  return __uint_as_float((unsigned)h << 16);
}

// ---------------- split-bf16 MFMA GEMM: Y = (X @ W + b) * scale
// mode: 0 = flat f32, 1 = headsplit f32, 2 = headsplit bf16
__global__ __launch_bounds__(256) void k_pmm(const float* __restrict__ X,
    const float* __restrict__ W, const float* __restrict__ bias,
    float* __restrict__ Y, float scale, int mode) {
  __shared__ ushort Ah[64][72], Al[64][72];   // X tile hi/lo: [row][k]
  __shared__ ushort Bh[64][72], Bl[64][72];   // W tile hi/lo TRANSPOSED: [col][k]
  int tid = threadIdx.x, lane = tid & 63, wid = tid >> 6;
  int r = tid >> 2, c0 = (tid & 3) * 16;
  int r0 = blockIdx.y * 64, n0 = blockIdx.x * 64;

  f32x4 acc[4];
  #pragma unroll
  for (int nc = 0; nc < 4; ++nc) acc[nc] = (f32x4){0.f, 0.f, 0.f, 0.f};

  for (int k0 = 0; k0 < EE; k0 += 64) {
    __syncthreads();
    {
      const float4* xs = (const float4*)(X + (size_t)(r0 + r) * EE + k0 + c0);
      #pragma unroll
      for (int q4 = 0; q4 < 4; ++q4) {
        float4 v = xs[q4];
        float f[4] = {v.x, v.y, v.z, v.w};
        ushort hi[4], lo[4];
        #pragma unroll
        for (int u = 0; u < 4; ++u) {
          hi[u] = f2bf(f[u]);
          lo[u] = f2bf(f[u] - bf2f(hi[u]));
        }
        *(unsigned*)&Ah[r][c0 + q4*4]     = (unsigned)hi[0] | ((unsigned)hi[1] << 16);
        *(unsigned*)&Ah[r][c0 + q4*4 + 2] = (unsigned)hi[2] | ((unsigned)hi[3] << 16);
        *(unsigned*)&Al[r][c0 + q4*4]     = (unsigned)lo[0] | ((unsigned)lo[1] << 16);
        *(unsigned*)&Al[r][c0 + q4*4 + 2] = (unsigned)lo[2] | ((unsigned)lo[3] << 16);
      }
    }
    {
      const float4* wsrc = (const float4*)(W + (size_t)(k0 + r) * EE + n0 + c0);
      #pragma unroll
      for (int q4 = 0; q4 < 4; ++q4) {
        float4 v = wsrc[q4];
        float f[4] = {v.x, v.y, v.z, v.w};
        #pragma unroll
        for (int u = 0; u < 4; ++u) {
          ushort hi = f2bf(f[u]);
          ushort lo = f2bf(f[u] - bf2f(hi));
          int c = c0 + q4*4 + u;
          Bh[c][r] = hi;
          Bl[c][r] = lo;
        }
      }
    }
    __syncthreads();
    #pragma unroll
    for (int kb = 0; kb < 2; ++kb) {
      bf16x8 ah = *(const bf16x8*)&Ah[wid*16 + (lane & 15)][kb*32 + (lane >> 4)*8];
      bf16x8 al = *(const bf16x8*)&Al[wid*16 + (lane & 15)][kb*32 + (lane >> 4)*8];
      #pragma unroll
      for (int nc = 0; nc < 4; ++nc) {
        bf16x8 bh_ = *(const bf16x8*)&Bh[nc*16 + (lane & 15)][kb*32 + (lane >> 4)*8];
        bf16x8 bl_ = *(const bf16x8*)&Bl[nc*16 + (lane & 15)][kb*32 + (lane >> 4)*8];
        acc[nc] = __builtin_amdgcn_mfma_f32_16x16x32_bf16(ah, bh_, acc[nc], 0, 0, 0);
        acc[nc] = __builtin_amdgcn_mfma_f32_16x16x32_bf16(al, bh_, acc[nc], 0, 0, 0);
        acc[nc] = __builtin_amdgcn_mfma_f32_16x16x32_bf16(ah, bl_, acc[nc], 0, 0, 0);
      }
    }
  }

  int rowbase = wid*16 + (lane >> 4)*4;
  #pragma unroll
  for (int nc = 0; nc < 4; ++nc) {
    int c = n0 + nc*16 + (lane & 15);
    float bv = bias[c];
    #pragma unroll
    for (int qq = 0; qq < 4; ++qq) {
      int rr = r0 + rowbase + qq;
      float val = (acc[nc][qq] + bv) * scale;
      int b_ = rr >> 10, t_ = rr & 1023, h_ = c >> 6, d_ = c & 63;
      if (mode == 1) {
        Y[(((size_t)(b_*HH + h_) * TT) + t_) * DD + d_] = val;
      } else if (mode == 2) {
        ((ushort*)Y)[(((size_t)(b_*HH + h_) * TT) + t_) * DD + d_] = f2bf(val);
      } else {
        Y[(size_t)rr * EE + c] = val;
      }
    }
  }
}

// ---------------- batched QK^T via split-bf16 MFMA (lower-triangle tiles)
__global__ __launch_bounds__(256) void k_qk_mfma(const float* __restrict__ q,
    const float* __restrict__ k, float* __restrict__ aw) {
  int bh = blockIdx.y, tt = blockIdx.x;
  int t0 = tt * 64;
  int tid = threadIdx.x, lane = tid & 63, wid = tid >> 6;
  int r = tid >> 2, c0 = (tid & 3) * 16;
  __shared__ ushort Qh[64][72], Ql[64][72];
  __shared__ ushort Kh[64][72], Kl[64][72];
  const float* qb = q + (size_t)bh * TT * DD;
  const float* kb = k + (size_t)bh * TT * DD;
  float* awb = aw + (size_t)bh * TT * TT;

  {
    const float4* xs = (const float4*)(qb + (size_t)(t0 + r) * DD + c0);
    #pragma unroll
    for (int q4 = 0; q4 < 4; ++q4) {
      float4 v = xs[q4];
      float f[4] = {v.x, v.y, v.z, v.w};
      ushort hi[4], lo[4];
      #pragma unroll
      for (int u = 0; u < 4; ++u) {
        hi[u] = f2bf(f[u]);
        lo[u] = f2bf(f[u] - bf2f(hi[u]));
      }
      *(unsigned*)&Qh[r][c0 + q4*4]     = (unsigned)hi[0] | ((unsigned)hi[1] << 16);
      *(unsigned*)&Qh[r][c0 + q4*4 + 2] = (unsigned)hi[2] | ((unsigned)hi[3] << 16);
      *(unsigned*)&Ql[r][c0 + q4*4]     = (unsigned)lo[0] | ((unsigned)lo[1] << 16);
      *(unsigned*)&Ql[r][c0 + q4*4 + 2] = (unsigned)lo[2] | ((unsigned)lo[3] << 16);
    }
  }

  for (int st = 0; st <= tt; ++st) {
    __syncthreads();
    {
      const float4* xs = (const float4*)(kb + (size_t)(st * 64 + r) * DD + c0);
      #pragma unroll
      for (int q4 = 0; q4 < 4; ++q4) {
        float4 v = xs[q4];
        float f[4] = {v.x, v.y, v.z, v.w};
        ushort hi[4], lo[4];
        #pragma unroll
        for (int u = 0; u < 4; ++u) {
          hi[u] = f2bf(f[u]);
          lo[u] = f2bf(f[u] - bf2f(hi[u]));
        }
        *(unsigned*)&Kh[r][c0 + q4*4]     = (unsigned)hi[0] | ((unsigned)hi[1] << 16);
        *(unsigned*)&Kh[r][c0 + q4*4 + 2] = (unsigned)hi[2] | ((unsigned)hi[3] << 16);
        *(unsigned*)&Kl[r][c0 + q4*4]     = (unsigned)lo[0] | ((unsigned)lo[1] << 16);
        *(unsigned*)&Kl[r][c0 + q4*4 + 2] = (unsigned)lo[2] | ((unsigned)lo[3] << 16);
      }
    }
    __syncthreads();
    f32x4 acc[4];
    #pragma unroll
    for (int nc = 0; nc < 4; ++nc) acc[nc] = (f32x4){0.f, 0.f, 0.f, 0.f};
    #pragma unroll
    for (int kb2 = 0; kb2 < 2; ++kb2) {
      bf16x8 ah = *(const bf16x8*)&Qh[wid*16 + (lane & 15)][kb2*32 + (lane >> 4)*8];
      bf16x8 al = *(const bf16x8*)&Ql[wid*16 + (lane & 15)][kb2*32 + (lane >> 4)*8];
      #pragma unroll
      for (int nc = 0; nc < 4; ++nc) {
        bf16x8 bh_ = *(const bf16x8*)&Kh[nc*16 + (lane & 15)][kb2*32 + (lane >> 4)*8];
        bf16x8 bl_ = *(const bf16x8*)&Kl[nc*16 + (lane & 15)][kb2*32 + (lane >> 4)*8];
        acc[nc] = __builtin_amdgcn_mfma_f32_16x16x32_bf16(ah, bh_, acc[nc], 0, 0, 0);
        acc[nc] = __builtin_amdgcn_mfma_f32_16x16x32_bf16(al, bh_, acc[nc], 0, 0, 0);
        acc[nc] = __builtin_amdgcn_mfma_f32_16x16x32_bf16(ah, bl_, acc[nc], 0, 0, 0);
      }
    }
    int rowbase = wid*16 + (lane >> 4)*4;
    #pragma unroll
    for (int nc = 0; nc < 4; ++nc) {
      int s = st * 64 + nc*16 + (lane & 15);
      #pragma unroll
      for (int qq = 0; qq < 4; ++qq) {
        int t_ = t0 + rowbase + qq;
        awb[(size_t)t_ * TT + s] = acc[nc][qq];
      }
    }
  }
}

// ---------------- row softmax in place: aw row -> probs (lower triangle only)
__global__ __launch_bounds__(256) void k_softmax(float* __restrict__ aw) {
  int bh = blockIdx.y;
  int wid = threadIdx.x >> 6, lane = threadIdx.x & 63;
  int t = blockIdx.x * 4 + wid;
  float* row = aw + ((size_t)bh * TT + t) * TT;
  float vals[16];
  float m = NEGF;
  #pragma unroll
  for (int i = 0; i < 16; ++i) {
    int j = lane + 64*i;
    vals[i] = (j <= t) ? row[j] : NEGF;
    m = fmaxf(m, vals[i]);
  }
  for (int o = 32; o; o >>= 1) m = fmaxf(m, __shfl_xor(m, o));
  float s = 0.f;
  #pragma unroll
  for (int i = 0; i < 16; ++i) {
    int j = lane + 64*i;
    if (j <= t) { vals[i] = expf(vals[i] - m); s += vals[i]; }
  }
  for (int o = 32; o; o >>= 1) s += __shfl_xor(s, o);
  float inv = 1.0f / s;
  #pragma unroll
  for (int i = 0; i < 16; ++i) {
    int j = lane + 64*i;
    if (j <= t) row[j] = vals[i] * inv;
  }
}

// ---------------- parallel init of heavy-hitter scores (p = probs)
__global__ __launch_bounds__(256) void k_init_acc(const float* __restrict__ p,
    float* __restrict__ initacc) {
  int bh = blockIdx.x;
  int c = threadIdx.x;
  float val = 0.f;
  if (c < HB) {
    const float* pb = p + (size_t)bh * TT * TT;
    for (int i = c; i < HB; ++i)
      val += pb[(size_t)i * TT + c];
  }
  initacc[(size_t)bh * 256 + c] = val;
}

// ---------------- wave-wide min over u32 via DPP (VALU path, no LDS)
#define DPP_HOP(ctrl)                                                        \
  {                                                                          \
    unsigned tt = (unsigned)__builtin_amdgcn_update_dpp(                     \
        (int)0xFFFFFFFFu, (int)x, (ctrl), 0xF, 0xF, false);                  \
    x = x < tt ? x : tt;                                                     \
  }
__device__ __forceinline__ unsigned wave_min_u32(unsigned x) {
  DPP_HOP(0x111)  // row_shr:1
  DPP_HOP(0x112)  // row_shr:2
  DPP_HOP(0x114)  // row_shr:4
  DPP_HOP(0x118)  // row_shr:8
  DPP_HOP(0x142)  // row_bcast:15
  DPP_HOP(0x143)  // row_bcast:31
  return (unsigned)__builtin_amdgcn_readlane((int)x, 63);
}

// global -> LDS direct DMA, 16B per lane
__device__ __forceinline__ void gload_lds16(const float* gsrc, float* ldst) {
  __builtin_amdgcn_global_load_lds(
      (const __attribute__((address_space(1))) unsigned int*)gsrc,
      (__attribute__((address_space(3))) unsigned int*)ldst,
      16, 0, 0);
}

// ---------------- serial heavy-hitter scan: SINGLE WAVE, self-paced DMA
// The wave issues its own global_load_lds prefetch (row t+INFLT, exactly 4
// loads per step) and gates on a hand-placed counted s_waitcnt vmcnt(28):
// vmcnt retires in issue order, so at step t the oldest 4 outstanding are
// row t's loads. Row reads are inline-asm ds_read_b32 (prevents hipcc from
// inserting its own vmcnt(0) before reads of the DMA-destination LDS); the
// DPP reduce overlaps their latency; lgkmcnt(0)+sched_barrier fences the
// select (rule: reg-only ops can hoist past inline-asm waits otherwise).
// No flags, no second wave, no deadlock modes: only vmcnt waits.
__global__ __launch_bounds__(64) void k_scan(const float* __restrict__ p,
    const float* __restrict__ initacc, int* __restrict__ evict_g) {
  int bh = blockIdx.x;
  int lane = threadIdx.x;
  const float* pb = p + (size_t)bh * TT * TT;
  __shared__ float ring[RING][TT];
  __shared__ int ev[TT];
  for (int i = lane; i < TT; i += 64) ev[i] = 0x7fffffff;

  // state (loaded BEFORE the DMA prologue so compiler waits don't drain DMA)
  bool act2 = lane < (HB - 128);   // lane < 25
  int col0 = lane, col1 = 64 + lane, col2 = act2 ? (128 + lane) : 0;
  float sc0 = initacc[(size_t)bh * 256 + lane];
  float sc1 = initacc[(size_t)bh * 256 + 64 + lane];
  float sc2 = act2 ? initacc[(size_t)bh * 256 + 128 + lane] : 0.f;

  unsigned ring_base = (unsigned)(size_t)(lds_float*)&ring[0][0];

  // prologue: issue rows HB..HB+INFLT-1 (32 loads outstanding)
  #pragma unroll
  for (int r = 0; r < INFLT; ++r) {
    const float* srcrow = pb + (size_t)(HB + r) * TT;
    float* slotbase = ring[(HB + r) & (RING - 1)];
    #pragma unroll
    for (int j = 0; j < 4; ++j)
      gload_lds16(srcrow + j * 256 + lane * 4, slotbase + j * 256);
  }

  for (int t = HB; t < TT; ++t) {
    // addresses for row t (slot t&15), from post-(t-1) cols
    unsigned sbase = ring_base + (unsigned)((t & (RING - 1)) * (TT * 4));
    unsigned a0 = sbase + (unsigned)col0 * 4;
    unsigned a1 = sbase + (unsigned)col1 * 4;
    unsigned a2 = sbase + (unsigned)col2 * 4;
    unsigned ad = sbase + (unsigned)t * 4;
    float r0, r1, r2, rd;
    asm volatile(
      "s_waitcnt vmcnt(28)\n\t"         // oldest 4 outstanding = row t: landed
      "ds_read_b32 %0, %4\n\t"
      "ds_read_b32 %1, %5\n\t"
      "ds_read_b32 %2, %6\n\t"
      "ds_read_b32 %3, %7"
      : "=&v"(r0), "=&v"(r1), "=&v"(r2), "=&v"(rd)
      : "v"(a0), "v"(a1), "v"(a2), "v"(ad)
      : "memory");
    // issue DMA for row t+INFLT (exactly 4 loads/step keeps vmcnt invariant;
    // tail: garbage refetch of row TT-1 into a consumer-dead slot)
    {
      int rn = t + INFLT;
      int rsrc = rn < TT ? rn : TT - 1;
      const float* srcrow = pb + (size_t)rsrc * TT;
      float* slotbase = ring[rn & (RING - 1)];
      #pragma unroll
      for (int j = 0; j < 4; ++j)
        gload_lds16(srcrow + j * 256 + lane * 4, slotbase + j * 256);
    }
    // DPP reduce (register-only; overlaps the ds_read latency)
    unsigned b0 = __float_as_uint(sc0);
    unsigned b1 = __float_as_uint(sc1);
    unsigned b2 = act2 ? __float_as_uint(sc2) : 0xFFFFFFFFu;
    unsigned mn = b0 < b1 ? b0 : b1; mn = mn < b2 ? mn : b2;
    unsigned mstar = wave_min_u32(mn);
    unsigned c0k = (b0 == mstar) ? (unsigned)(1023 - col0) : 0xFFFFFFFFu;
    unsigned c1k = (b1 == mstar) ? (unsigned)(1023 - col1) : 0xFFFFFFFFu;
    unsigned c2k = (act2 && b2 == mstar) ? (unsigned)(1023 - col2) : 0xFFFFFFFFu;
    unsigned cm = c0k < c1k ? c0k : c1k; cm = cm < c2k ? cm : c2k;
    int cstar = 1023 - (int)wave_min_u32(cm);
    // fence: ds_read results must be architecturally complete before select
    asm volatile("s_waitcnt lgkmcnt(0)" ::: "memory");
    __builtin_amdgcn_sched_barrier(0);
    // select (cols are a distinct set -> col==cstar suffices)
    if (col0 == cstar) { ev[col0] = t; col0 = t; sc0 = rd; } else sc0 += r0;
    if (col1 == cstar) { ev[col1] = t; col1 = t; sc1 = rd; } else sc1 += r1;
    if (act2) {
      if (col2 == cstar) { ev[col2] = t; col2 = t; sc2 = rd; } else sc2 += r2;
    }
  }

  int4* dst4 = (int4*)(evict_g + (size_t)bh * TT);
  const int4* src4 = (const int4*)ev;
  #pragma unroll
  for (int i = 0; i < 4; ++i) dst4[lane + 64 * i] = src4[lane + 64 * i];
}

// ---------------- fused mask + renorm + PV via bf16 MFMA
__global__ __launch_bounds__(256) void k_pv(const float* __restrict__ p,
    const int* __restrict__ evict_g, const ushort* __restrict__ vbf,
    float* __restrict__ ao) {
  int bh = blockIdx.y, tt = blockIdx.x;
  int tid = threadIdx.x, lane = tid & 63, wid = tid >> 6;
  int t0 = tt * 64;
  __shared__ ushort PA[64][72];   // masked bf16 P tile
  __shared__ ushort VT[64][72];   // V tile transposed: VT[d][s]
  __shared__ float rowsum[64];
  __shared__ int et[TT];
  ((int4*)et)[tid] = ((const int4*)(evict_g + (size_t)bh * TT))[tid];
  if (tid < 64) rowsum[tid] = 0.f;
  const float* pb = p + ((size_t)bh * TT + t0) * TT;
  const ushort* vb = vbf + (size_t)bh * TT * DD;

  f32x4 acc[4];
  #pragma unroll
  for (int nc = 0; nc < 4; ++nc) acc[nc] = (f32x4){0.f, 0.f, 0.f, 0.f};

  int r = tid >> 2;
  int c0 = (tid & 3) * 16;
  int tg = t0 + r;
  __syncthreads();

  for (int st = 0; st <= tt; ++st) {
    const float* prow = pb + (size_t)r * TT + st * 64 + c0;
    float part = 0.f;
    ushort tmp16[16];
    #pragma unroll
    for (int q4 = 0; q4 < 4; ++q4) {
      float4 pv4 = *(const float4*)(prow + q4 * 4);
      float vals[4] = {pv4.x, pv4.y, pv4.z, pv4.w};
      #pragma unroll
      for (int u = 0; u < 4; ++u) {
        int j = st * 64 + c0 + q4 * 4 + u;
        bool allow = (j <= tg) && ((et[j] > tg) || (j + RECW >= tg));
        float mv = allow ? vals[u] : 0.f;
        part += mv;
        tmp16[q4 * 4 + u] = f2bf(mv);
      }
    }
    #pragma unroll
    for (int w2 = 0; w2 < 8; ++w2) {
      unsigned pk = (unsigned)tmp16[w2 * 2] | ((unsigned)tmp16[w2 * 2 + 1] << 16);
      *(unsigned*)&PA[r][c0 + w2 * 2] = pk;
    }
    part += __shfl_xor(part, 1);
    part += __shfl_xor(part, 2);
    if ((tid & 3) == 0) rowsum[r] += part;
    {
      const unsigned* vrow32 = (const unsigned*)(vb + (size_t)(st * 64 + r) * DD + c0);
      #pragma unroll
      for (int u = 0; u < 8; ++u) {
        unsigned vv = vrow32[u];
        VT[c0 + u * 2][r] = (ushort)(vv & 0xFFFF);
        VT[c0 + u * 2 + 1][r] = (ushort)(vv >> 16);
      }
    }
    __syncthreads();
    #pragma unroll
    for (int kb = 0; kb < 2; ++kb) {
      bf16x8 af = *(const bf16x8*)&PA[wid * 16 + (lane & 15)][kb * 32 + (lane >> 4) * 8];
      #pragma unroll
      for (int nc = 0; nc < 4; ++nc) {
        bf16x8 bfr = *(const bf16x8*)&VT[nc * 16 + (lane & 15)][kb * 32 + (lane >> 4) * 8];
        acc[nc] = __builtin_amdgcn_mfma_f32_16x16x32_bf16(af, bfr, acc[nc], 0, 0, 0);
      }
    }
    __syncthreads();
  }

  int b_ = bh >> 4, h_ = bh & 15;
  int rl = wid * 16 + (lane >> 4) * 4;
  #pragma unroll
  for (int nc = 0; nc < 4; ++nc) {
    int d = nc * 16 + (lane & 15);
    #pragma unroll
    for (int qq = 0; qq < 4; ++qq) {
      int rr = rl + qq;
      float outv = acc[nc][qq] / rowsum[rr];
      ao[((size_t)b_ * TT + (t0 + rr)) * EE + h_ * DD + d] = outv;
    }
  }
}

extern "C" void kernel_launch(void* const* d_in, const int* in_sizes, int n_in,
                              void* d_out, int out_size, void* d_ws, size_t ws_size,
                              hipStream_t stream) {
  const float* hs = (const float*)d_in[0];
  const float* Wq = (const float*)d_in[2];
  const float* bq = (const float*)d_in[3];
  const float* Wk = (const float*)d_in[4];
  const float* bk = (const float*)d_in[5];
  const float* Wv = (const float*)d_in[6];
  const float* bv = (const float*)d_in[7];
  const float* Wo = (const float*)d_in[8];
  const float* bo = (const float*)d_in[9];
  float* out = (float*)d_out;

  float* ws = (float*)d_ws;
  float* q  = ws + OFF_Q;
  float* k  = ws + OFF_K;
  float* v  = ws + OFF_V;     // holds bf16 V (ushort)
  float* aw = ws + OFF_AW;    // becomes probs after k_softmax
  float* ao = ws + OFF_AO;
  float* initacc = ws + OFF_END;
  int* evict = (int*)(ws + OFF_END + (size_t)BHN * 256);

  dim3 gproj(16, 32);
  k_pmm<<<gproj, 256, 0, stream>>>(hs, Wq, bq, q, 0.125f, 1);
  k_pmm<<<gproj, 256, 0, stream>>>(hs, Wk, bk, k, 1.0f, 1);
  k_pmm<<<gproj, 256, 0, stream>>>(hs, Wv, bv, v, 1.0f, 2);   // bf16 head-split

  dim3 gqk(16, BHN);
  k_qk_mfma<<<gqk, 256, 0, stream>>>(q, k, aw);

  dim3 grs(TT/4, BHN);
  k_softmax<<<grs, 256, 0, stream>>>(aw);

  k_init_acc<<<BHN, 256, 0, stream>>>(aw, initacc);

  k_scan<<<BHN, 64, 0, stream>>>(aw, initacc, evict);

  dim3 gpv(16, BHN);
  k_pv<<<gpv, 256, 0, stream>>>(aw, evict, (const ushort*)v, ao);

  dim3 gout(16, 32);
  k_pmm<<<gout, 256, 0, stream>>>(ao, Wo, bo, out, 1.0f, 0);
}

// Round 13
// 572.219 us; speedup vs baseline: 2.4957x; 1.0315x over previous
//
#include <hip/hip_runtime.h>
#include <hip/hip_bf16.h>
#include <stdint.h>

#define TT 1024
#define EE 1024
#define HH 16
#define DD 64
#define BHN 32
#define HB 153
#define RECW 102
#define RING 16
#define INFLT 8
#define NEGF (-3.4028234663852886e38f)

typedef unsigned long long ull;
typedef __attribute__((ext_vector_type(8))) short bf16x8;
typedef __attribute__((ext_vector_type(4))) float f32x4;
typedef __attribute__((address_space(3))) float lds_float;

// workspace layout (float element offsets)
#define OFF_Q  ((size_t)0)
#define OFF_K  (OFF_Q + (size_t)BHN*TT*DD)
#define OFF_V  (OFF_K + (size_t)BHN*TT*DD)   // reused as bf16 (ushort) buffer
#define OFF_AW (OFF_V + (size_t)BHN*TT*DD)
#define OFF_M  (OFF_AW + (size_t)BHN*TT*TT)
#define OFF_S  (OFF_M + (size_t)BHN*TT)
#define OFF_AO (OFF_S + (size_t)BHN*TT)
#define OFF_END (OFF_AO + (size_t)BHN*TT*DD)
// after OFF_END: initacc float[BHN*256], evict int[BHN*1024]

__device__ __forceinline__ ushort f2bf(float x) {
  unsigned u = __float_as_uint(x);
  u = (u + 0x7FFF + ((u >> 16) & 1)) >> 16;   // RNE
  return (ushort)u;
}
__device__ __forceinline__ float bf2f(ushort h) {
  return __uint_as_float((unsigned)h << 16);
}

// ---------------- split-bf16 MFMA GEMM: Y = (X @ W + b) * scale
// mode: 0 = flat f32, 1 = headsplit f32, 2 = headsplit bf16
__global__ __launch_bounds__(256) void k_pmm(const float* __restrict__ X,
    const float* __restrict__ W, const float* __restrict__ bias,
    float* __restrict__ Y, float scale, int mode) {
  __shared__ ushort Ah[64][72], Al[64][72];   // X tile hi/lo: [row][k]
  __shared__ ushort Bh[64][72], Bl[64][72];   // W tile hi/lo TRANSPOSED: [col][k]
  int tid = threadIdx.x, lane = tid & 63, wid = tid >> 6;
  int r = tid >> 2, c0 = (tid & 3) * 16;
  int r0 = blockIdx.y * 64, n0 = blockIdx.x * 64;

  f32x4 acc[4];
  #pragma unroll
  for (int nc = 0; nc < 4; ++nc) acc[nc] = (f32x4){0.f, 0.f, 0.f, 0.f};

  for (int k0 = 0; k0 < EE; k0 += 64) {
    __syncthreads();
    {
      const float4* xs = (const float4*)(X + (size_t)(r0 + r) * EE + k0 + c0);
      #pragma unroll
      for (int q4 = 0; q4 < 4; ++q4) {
        float4 v = xs[q4];
        float f[4] = {v.x, v.y, v.z, v.w};
        ushort hi[4], lo[4];
        #pragma unroll
        for (int u = 0; u < 4; ++u) {
          hi[u] = f2bf(f[u]);
          lo[u] = f2bf(f[u] - bf2f(hi[u]));
        }
        *(unsigned*)&Ah[r][c0 + q4*4]     = (unsigned)hi[0] | ((unsigned)hi[1] << 16);
        *(unsigned*)&Ah[r][c0 + q4*4 + 2] = (unsigned)hi[2] | ((unsigned)hi[3] << 16);
        *(unsigned*)&Al[r][c0 + q4*4]     = (unsigned)lo[0] | ((unsigned)lo[1] << 16);
        *(unsigned*)&Al[r][c0 + q4*4 + 2] = (unsigned)lo[2] | ((unsigned)lo[3] << 16);
      }
    }
    {
      const float4* wsrc = (const float4*)(W + (size_t)(k0 + r) * EE + n0 + c0);
      #pragma unroll
      for (int q4 = 0; q4 < 4; ++q4) {
        float4 v = wsrc[q4];
        float f[4] = {v.x, v.y, v.z, v.w};
        #pragma unroll
        for (int u = 0; u < 4; ++u) {
          ushort hi = f2bf(f[u]);
          ushort lo = f2bf(f[u] - bf2f(hi));
          int c = c0 + q4*4 + u;
          Bh[c][r] = hi;
          Bl[c][r] = lo;
        }
      }
    }
    __syncthreads();
    #pragma unroll
    for (int kb = 0; kb < 2; ++kb) {
      bf16x8 ah = *(const bf16x8*)&Ah[wid*16 + (lane & 15)][kb*32 + (lane >> 4)*8];
      bf16x8 al = *(const bf16x8*)&Al[wid*16 + (lane & 15)][kb*32 + (lane >> 4)*8];
      #pragma unroll
      for (int nc = 0; nc < 4; ++nc) {
        bf16x8 bh_ = *(const bf16x8*)&Bh[nc*16 + (lane & 15)][kb*32 + (lane >> 4)*8];
        bf16x8 bl_ = *(const bf16x8*)&Bl[nc*16 + (lane & 15)][kb*32 + (lane >> 4)*8];
        acc[nc] = __builtin_amdgcn_mfma_f32_16x16x32_bf16(ah, bh_, acc[nc], 0, 0, 0);
        acc[nc] = __builtin_amdgcn_mfma_f32_16x16x32_bf16(al, bh_, acc[nc], 0, 0, 0);
        acc[nc] = __builtin_amdgcn_mfma_f32_16x16x32_bf16(ah, bl_, acc[nc], 0, 0, 0);
      }
    }
  }

  int rowbase = wid*16 + (lane >> 4)*4;
  #pragma unroll
  for (int nc = 0; nc < 4; ++nc) {
    int c = n0 + nc*16 + (lane & 15);
    float bv = bias[c];
    #pragma unroll
    for (int qq = 0; qq < 4; ++qq) {
      int rr = r0 + rowbase + qq;
      float val = (acc[nc][qq] + bv) * scale;
      int b_ = rr >> 10, t_ = rr & 1023, h_ = c >> 6, d_ = c & 63;
      if (mode == 1) {
        Y[(((size_t)(b_*HH + h_) * TT) + t_) * DD + d_] = val;
      } else if (mode == 2) {
        ((ushort*)Y)[(((size_t)(b_*HH + h_) * TT) + t_) * DD + d_] = f2bf(val);
      } else {
        Y[(size_t)rr * EE + c] = val;
      }
    }
  }
}

// ---------------- batched QK^T via split-bf16 MFMA (lower-triangle tiles)
__global__ __launch_bounds__(256) void k_qk_mfma(const float* __restrict__ q,
    const float* __restrict__ k, float* __restrict__ aw) {
  int bh = blockIdx.y, tt = blockIdx.x;
  int t0 = tt * 64;
  int tid = threadIdx.x, lane = tid & 63, wid = tid >> 6;
  int r = tid >> 2, c0 = (tid & 3) * 16;
  __shared__ ushort Qh[64][72], Ql[64][72];
  __shared__ ushort Kh[64][72], Kl[64][72];
  const float* qb = q + (size_t)bh * TT * DD;
  const float* kb = k + (size_t)bh * TT * DD;
  float* awb = aw + (size_t)bh * TT * TT;

  {
    const float4* xs = (const float4*)(qb + (size_t)(t0 + r) * DD + c0);
    #pragma unroll
    for (int q4 = 0; q4 < 4; ++q4) {
      float4 v = xs[q4];
      float f[4] = {v.x, v.y, v.z, v.w};
      ushort hi[4], lo[4];
      #pragma unroll
      for (int u = 0; u < 4; ++u) {
        hi[u] = f2bf(f[u]);
        lo[u] = f2bf(f[u] - bf2f(hi[u]));
      }
      *(unsigned*)&Qh[r][c0 + q4*4]     = (unsigned)hi[0] | ((unsigned)hi[1] << 16);
      *(unsigned*)&Qh[r][c0 + q4*4 + 2] = (unsigned)hi[2] | ((unsigned)hi[3] << 16);
      *(unsigned*)&Ql[r][c0 + q4*4]     = (unsigned)lo[0] | ((unsigned)lo[1] << 16);
      *(unsigned*)&Ql[r][c0 + q4*4 + 2] = (unsigned)lo[2] | ((unsigned)lo[3] << 16);
    }
  }

  for (int st = 0; st <= tt; ++st) {
    __syncthreads();
    {
      const float4* xs = (const float4*)(kb + (size_t)(st * 64 + r) * DD + c0);
      #pragma unroll
      for (int q4 = 0; q4 < 4; ++q4) {
        float4 v = xs[q4];
        float f[4] = {v.x, v.y, v.z, v.w};
        ushort hi[4], lo[4];
        #pragma unroll
        for (int u = 0; u < 4; ++u) {
          hi[u] = f2bf(f[u]);
          lo[u] = f2bf(f[u] - bf2f(hi[u]));
        }
        *(unsigned*)&Kh[r][c0 + q4*4]     = (unsigned)hi[0] | ((unsigned)hi[1] << 16);
        *(unsigned*)&Kh[r][c0 + q4*4 + 2] = (unsigned)hi[2] | ((unsigned)hi[3] << 16);
        *(unsigned*)&Kl[r][c0 + q4*4]     = (unsigned)lo[0] | ((unsigned)lo[1] << 16);
        *(unsigned*)&Kl[r][c0 + q4*4 + 2] = (unsigned)lo[2] | ((unsigned)lo[3] << 16);
      }
    }
    __syncthreads();
    f32x4 acc[4];
    #pragma unroll
    for (int nc = 0; nc < 4; ++nc) acc[nc] = (f32x4){0.f, 0.f, 0.f, 0.f};
    #pragma unroll
    for (int kb2 = 0; kb2 < 2; ++kb2) {
      bf16x8 ah = *(const bf16x8*)&Qh[wid*16 + (lane & 15)][kb2*32 + (lane >> 4)*8];
      bf16x8 al = *(const bf16x8*)&Ql[wid*16 + (lane & 15)][kb2*32 + (lane >> 4)*8];
      #pragma unroll
      for (int nc = 0; nc < 4; ++nc) {
        bf16x8 bh_ = *(const bf16x8*)&Kh[nc*16 + (lane & 15)][kb2*32 + (lane >> 4)*8];
        bf16x8 bl_ = *(const bf16x8*)&Kl[nc*16 + (lane & 15)][kb2*32 + (lane >> 4)*8];
        acc[nc] = __builtin_amdgcn_mfma_f32_16x16x32_bf16(ah, bh_, acc[nc], 0, 0, 0);
        acc[nc] = __builtin_amdgcn_mfma_f32_16x16x32_bf16(al, bh_, acc[nc], 0, 0, 0);
        acc[nc] = __builtin_amdgcn_mfma_f32_16x16x32_bf16(ah, bl_, acc[nc], 0, 0, 0);
      }
    }
    int rowbase = wid*16 + (lane >> 4)*4;
    #pragma unroll
    for (int nc = 0; nc < 4; ++nc) {
      int s = st * 64 + nc*16 + (lane & 15);
      #pragma unroll
      for (int qq = 0; qq < 4; ++qq) {
        int t_ = t0 + rowbase + qq;
        awb[(size_t)t_ * TT + s] = acc[nc][qq];
      }
    }
  }
}

// ---------------- row softmax in place: aw row -> probs (lower triangle only)
__global__ __launch_bounds__(256) void k_softmax(float* __restrict__ aw) {
  int bh = blockIdx.y;
  int wid = threadIdx.x >> 6, lane = threadIdx.x & 63;
  int t = blockIdx.x * 4 + wid;
  float* row = aw + ((size_t)bh * TT + t) * TT;
  float vals[16];
  float m = NEGF;
  #pragma unroll
  for (int i = 0; i < 16; ++i) {
    int j = lane + 64*i;
    vals[i] = (j <= t) ? row[j] : NEGF;
    m = fmaxf(m, vals[i]);
  }
  for (int o = 32; o; o >>= 1) m = fmaxf(m, __shfl_xor(m, o));
  float s = 0.f;
  #pragma unroll
  for (int i = 0; i < 16; ++i) {
    int j = lane + 64*i;
    if (j <= t) { vals[i] = expf(vals[i] - m); s += vals[i]; }
  }
  for (int o = 32; o; o >>= 1) s += __shfl_xor(s, o);
  float inv = 1.0f / s;
  #pragma unroll
  for (int i = 0; i < 16; ++i) {
    int j = lane + 64*i;
    if (j <= t) row[j] = vals[i] * inv;
  }
}

// ---------------- parallel init of heavy-hitter scores (p = probs)
__global__ __launch_bounds__(256) void k_init_acc(const float* __restrict__ p,
    float* __restrict__ initacc) {
  int bh = blockIdx.x;
  int c = threadIdx.x;
  float val = 0.f;
  if (c < HB) {
    const float* pb = p + (size_t)bh * TT * TT;
    for (int i = c; i < HB; ++i)
      val += pb[(size_t)i * TT + c];
  }
  initacc[(size_t)bh * 256 + c] = val;
}

// ---------------- wave-wide min over u32 via DPP (VALU path, no LDS)
#define DPP_HOP(ctrl)                                                        \
  {                                                                          \
    unsigned tt = (unsigned)__builtin_amdgcn_update_dpp(                     \
        (int)0xFFFFFFFFu, (int)x, (ctrl), 0xF, 0xF, false);                  \
    x = x < tt ? x : tt;                                                     \
  }
__device__ __forceinline__ unsigned wave_min_u32(unsigned x) {
  DPP_HOP(0x111)  // row_shr:1
  DPP_HOP(0x112)  // row_shr:2
  DPP_HOP(0x114)  // row_shr:4
  DPP_HOP(0x118)  // row_shr:8
  DPP_HOP(0x142)  // row_bcast:15
  DPP_HOP(0x143)  // row_bcast:31
  return (unsigned)__builtin_amdgcn_readlane((int)x, 63);
}

// global -> LDS direct DMA, 16B per lane
__device__ __forceinline__ void gload_lds16(const float* gsrc, float* ldst) {
  __builtin_amdgcn_global_load_lds(
      (const __attribute__((address_space(1))) unsigned int*)gsrc,
      (__attribute__((address_space(3))) unsigned int*)ldst,
      16, 0, 0);
}

// ---------------- serial heavy-hitter scan: SINGLE WAVE, self-paced DMA,
// read-ahead pipeline. Key ideas:
//  * reads for row t+1 are issued BEFORE select(t): evicted slot's new col is
//    always t, so {old cols, diag t+1, candidate t} cover both outcomes; a
//    cndmask patch after the wait picks the right value (select -> addr ->
//    ds_read removed from the serial chain).
//  * NO "memory" clobbers on the asm: hipcc's legalizer otherwise drains
//    vmcnt(0) before memory-clobber asm (round-12's ~800cy/step residual).
//    Volatile<->volatile asm order still holds; DMA hoisting past the counted
//    wait only strengthens it.
//  * tie-skip: if the min-score match is globally unique (ballot check), skip
//    the 2nd DPP reduce; fallback preserves exact reference tie-break.
__global__ __launch_bounds__(64) void k_scan(const float* __restrict__ p,
    const float* __restrict__ initacc, int* __restrict__ evict_g) {
  int bh = blockIdx.x;
  int lane = threadIdx.x;
  const float* pb = p + (size_t)bh * TT * TT;
  __shared__ float ring[RING][TT];
  __shared__ int ev[TT];
  for (int i = lane; i < TT; i += 64) ev[i] = 0x7fffffff;

  bool act2 = lane < (HB - 128);   // lane < 25
  int col0 = lane, col1 = 64 + lane, col2 = act2 ? (128 + lane) : 0;
  float sc0 = initacc[(size_t)bh * 256 + lane];
  float sc1 = initacc[(size_t)bh * 256 + 64 + lane];
  float sc2 = act2 ? initacc[(size_t)bh * 256 + 128 + lane] : 0.f;

  unsigned ring_base = (unsigned)(size_t)(lds_float*)&ring[0][0];

  // prologue: issue rows HB..HB+7 (32 loads outstanding)
  #pragma unroll
  for (int r = 0; r < INFLT; ++r) {
    const float* srcrow = pb + (size_t)(HB + r) * TT;
    float* slotbase = ring[(HB + r) & (RING - 1)];
    #pragma unroll
    for (int j = 0; j < 4; ++j)
      gload_lds16(srcrow + j * 256 + lane * 4, slotbase + j * 256);
  }
  // row HB landed; issue its 5 reads (candidate read harmless/unused at t=HB)
  float r0, r1, r2, rd, re;
  {
    unsigned sbase = ring_base + (unsigned)((HB & (RING - 1)) * (TT * 4));
    unsigned a0 = sbase + (unsigned)col0 * 4;
    unsigned a1 = sbase + (unsigned)col1 * 4;
    unsigned a2 = sbase + (unsigned)col2 * 4;
    unsigned ad = sbase + (unsigned)HB * 4;
    unsigned ae = sbase + (unsigned)(HB - 1) * 4;
    asm volatile("s_waitcnt vmcnt(28)");
    asm volatile(
      "ds_read_b32 %0, %5\n\t"
      "ds_read_b32 %1, %6\n\t"
      "ds_read_b32 %2, %7\n\t"
      "ds_read_b32 %3, %8\n\t"
      "ds_read_b32 %4, %9"
      : "=&v"(r0), "=&v"(r1), "=&v"(r2), "=&v"(rd), "=&v"(re)
      : "v"(a0), "v"(a1), "v"(a2), "v"(ad), "v"(ae));
  }
  bool e0p = false, e1p = false, e2p = false;

  for (int t = HB; t < TT; ++t) {
    int tn = (t + 1 < TT) ? (t + 1) : (TT - 1);   // clamped: garbage re-read at tail
    // (1) ensure row t+1 landed (outstanding rows t+1..t+7 = 28; retire oldest 4)
    asm volatile("s_waitcnt vmcnt(24)");
    // (2) issue reads for row t+1 at PRE-select cols + diag + evict-candidate
    float n0, n1, n2, nd, ne;
    {
      unsigned sbase = ring_base + (unsigned)((tn & (RING - 1)) * (TT * 4));
      unsigned a0 = sbase + (unsigned)col0 * 4;
      unsigned a1 = sbase + (unsigned)col1 * 4;
      unsigned a2 = sbase + (unsigned)col2 * 4;
      unsigned ad = sbase + (unsigned)tn * 4;
      unsigned ae = sbase + (unsigned)t * 4;
      asm volatile(
        "ds_read_b32 %0, %5\n\t"
        "ds_read_b32 %1, %6\n\t"
        "ds_read_b32 %2, %7\n\t"
        "ds_read_b32 %3, %8\n\t"
        "ds_read_b32 %4, %9"
        : "=&v"(n0), "=&v"(n1), "=&v"(n2), "=&v"(nd), "=&v"(ne)
        : "v"(a0), "v"(a1), "v"(a2), "v"(ad), "v"(ae));
    }
    // (3) issue DMA for row t+8 (exactly 4 loads/step keeps vmcnt invariant)
    {
      int rn = t + INFLT;
      int rsrc = rn < TT ? rn : TT - 1;
      const float* srcrow = pb + (size_t)rsrc * TT;
      float* slotbase = ring[rn & (RING - 1)];
      #pragma unroll
      for (int j = 0; j < 4; ++j)
        gload_lds16(srcrow + j * 256 + lane * 4, slotbase + j * 256);
    }
    // (4) reduce for step t (keys = scores BEFORE adding row t, as in reference)
    unsigned b0 = __float_as_uint(sc0);
    unsigned b1 = __float_as_uint(sc1);
    unsigned b2 = act2 ? __float_as_uint(sc2) : 0xFFFFFFFFu;
    unsigned mn = b0 < b1 ? b0 : b1; mn = mn < b2 ? mn : b2;
    unsigned mstar = wave_min_u32(mn);
    bool m0 = (b0 == mstar), m1 = (b1 == mstar), m2 = act2 && (b2 == mstar);
    int lcl = (int)m0 + (int)m1 + (int)m2;
    ull bal1 = __ballot(lcl >= 1);
    ull bal2 = __ballot(lcl >= 2);
    bool e0, e1, e2;
    if (bal2 == 0 && __popcll(bal1) == 1) {
      // unique min: no tie-break reduce needed
      e0 = m0; e1 = m1; e2 = m2;
    } else {
      // tie: evict the LARGEST col among matches (ref top_k keeps lower idx)
      unsigned c0k = m0 ? (unsigned)(1023 - col0) : 0xFFFFFFFFu;
      unsigned c1k = m1 ? (unsigned)(1023 - col1) : 0xFFFFFFFFu;
      unsigned c2k = m2 ? (unsigned)(1023 - col2) : 0xFFFFFFFFu;
      unsigned cm = c0k < c1k ? c0k : c1k; cm = cm < c2k ? cm : c2k;
      int cstar = 1023 - (int)wave_min_u32(cm);
      e0 = m0 && (col0 == cstar);
      e1 = m1 && (col1 == cstar);
      e2 = m2 && (col2 == cstar);
    }
    // (5) row-t reads (issued last iter) are long done; drain and fence
    asm volatile("s_waitcnt lgkmcnt(0)");
    __builtin_amdgcn_sched_barrier(0);
    // patch: slot evicted at t-1 moved to col t-1 -> its row-t value is re
    float rr0 = e0p ? re : r0;
    float rr1 = e1p ? re : r1;
    float rr2 = e2p ? re : r2;
    // (6) select
    if (e0) { ev[col0] = t; col0 = t; sc0 = rd; } else sc0 += rr0;
    if (e1) { ev[col1] = t; col1 = t; sc1 = rd; } else sc1 += rr1;
    if (act2) {
      if (e2) { ev[col2] = t; col2 = t; sc2 = rd; } else sc2 += rr2;
    }
    e0p = e0; e1p = e1; e2p = e2;
    r0 = n0; r1 = n1; r2 = n2; rd = nd; re = ne;
  }

  int4* dst4 = (int4*)(evict_g + (size_t)bh * TT);
  const int4* src4 = (const int4*)ev;
  #pragma unroll
  for (int i = 0; i < 4; ++i) dst4[lane + 64 * i] = src4[lane + 64 * i];
}

// ---------------- fused mask + renorm + PV via bf16 MFMA
__global__ __launch_bounds__(256) void k_pv(const float* __restrict__ p,
    const int* __restrict__ evict_g, const ushort* __restrict__ vbf,
    float* __restrict__ ao) {
  int bh = blockIdx.y, tt = blockIdx.x;
  int tid = threadIdx.x, lane = tid & 63, wid = tid >> 6;
  int t0 = tt * 64;
  __shared__ ushort PA[64][72];   // masked bf16 P tile
  __shared__ ushort VT[64][72];   // V tile transposed: VT[d][s]
  __shared__ float rowsum[64];
  __shared__ int et[TT];
  ((int4*)et)[tid] = ((const int4*)(evict_g + (size_t)bh * TT))[tid];
  if (tid < 64) rowsum[tid] = 0.f;
  const float* pb = p + ((size_t)bh * TT + t0) * TT;
  const ushort* vb = vbf + (size_t)bh * TT * DD;

  f32x4 acc[4];
  #pragma unroll
  for (int nc = 0; nc < 4; ++nc) acc[nc] = (f32x4){0.f, 0.f, 0.f, 0.f};

  int r = tid >> 2;
  int c0 = (tid & 3) * 16;
  int tg = t0 + r;
  __syncthreads();

  for (int st = 0; st <= tt; ++st) {
    const float* prow = pb + (size_t)r * TT + st * 64 + c0;
    float part = 0.f;
    ushort tmp16[16];
    #pragma unroll
    for (int q4 = 0; q4 < 4; ++q4) {
      float4 pv4 = *(const float4*)(prow + q4 * 4);
      float vals[4] = {pv4.x, pv4.y, pv4.z, pv4.w};
      #pragma unroll
      for (int u = 0; u < 4; ++u) {
        int j = st * 64 + c0 + q4 * 4 + u;
        bool allow = (j <= tg) && ((et[j] > tg) || (j + RECW >= tg));
        float mv = allow ? vals[u] : 0.f;
        part += mv;
        tmp16[q4 * 4 + u] = f2bf(mv);
      }
    }
    #pragma unroll
    for (int w2 = 0; w2 < 8; ++w2) {
      unsigned pk = (unsigned)tmp16[w2 * 2] | ((unsigned)tmp16[w2 * 2 + 1] << 16);
      *(unsigned*)&PA[r][c0 + w2 * 2] = pk;
    }
    part += __shfl_xor(part, 1);
    part += __shfl_xor(part, 2);
    if ((tid & 3) == 0) rowsum[r] += part;
    {
      const unsigned* vrow32 = (const unsigned*)(vb + (size_t)(st * 64 + r) * DD + c0);
      #pragma unroll
      for (int u = 0; u < 8; ++u) {
        unsigned vv = vrow32[u];
        VT[c0 + u * 2][r] = (ushort)(vv & 0xFFFF);
        VT[c0 + u * 2 + 1][r] = (ushort)(vv >> 16);
      }
    }
    __syncthreads();
    #pragma unroll
    for (int kb = 0; kb < 2; ++kb) {
      bf16x8 af = *(const bf16x8*)&PA[wid * 16 + (lane & 15)][kb * 32 + (lane >> 4) * 8];
      #pragma unroll
      for (int nc = 0; nc < 4; ++nc) {
        bf16x8 bfr = *(const bf16x8*)&VT[nc * 16 + (lane & 15)][kb * 32 + (lane >> 4) * 8];
        acc[nc] = __builtin_amdgcn_mfma_f32_16x16x32_bf16(af, bfr, acc[nc], 0, 0, 0);
      }
    }
    __syncthreads();
  }

  int b_ = bh >> 4, h_ = bh & 15;
  int rl = wid * 16 + (lane >> 4) * 4;
  #pragma unroll
  for (int nc = 0; nc < 4; ++nc) {
    int d = nc * 16 + (lane & 15);
    #pragma unroll
    for (int qq = 0; qq < 4; ++qq) {
      int rr = rl + qq;
      float outv = acc[nc][qq] / rowsum[rr];
      ao[((size_t)b_ * TT + (t0 + rr)) * EE + h_ * DD + d] = outv;
    }
  }
}

extern "C" void kernel_launch(void* const* d_in, const int* in_sizes, int n_in,
                              void* d_out, int out_size, void* d_ws, size_t ws_size,
                              hipStream_t stream) {
  const float* hs = (const float*)d_in[0];
  const float* Wq = (const float*)d_in[2];
  const float* bq = (const float*)d_in[3];
  const float* Wk = (const float*)d_in[4];
  const float* bk = (const float*)d_in[5];
  const float* Wv = (const float*)d_in[6];
  const float* bv = (const float*)d_in[7];
  const float* Wo = (const float*)d_in[8];
  const float* bo = (const float*)d_in[9];
  float* out = (float*)d_out;

  float* ws = (float*)d_ws;
  float* q  = ws + OFF_Q;
  float* k  = ws + OFF_K;
  float* v  = ws + OFF_V;     // holds bf16 V (ushort)
  float* aw = ws + OFF_AW;    // becomes probs after k_softmax
  float* ao = ws + OFF_AO;
  float* initacc = ws + OFF_END;
  int* evict = (int*)(ws + OFF_END + (size_t)BHN * 256);

  dim3 gproj(16, 32);
  k_pmm<<<gproj, 256, 0, stream>>>(hs, Wq, bq, q, 0.125f, 1);
  k_pmm<<<gproj, 256, 0, stream>>>(hs, Wk, bk, k, 1.0f, 1);
  k_pmm<<<gproj, 256, 0, stream>>>(hs, Wv, bv, v, 1.0f, 2);   // bf16 head-split

  dim3 gqk(16, BHN);
  k_qk_mfma<<<gqk, 256, 0, stream>>>(q, k, aw);

  dim3 grs(TT/4, BHN);
  k_softmax<<<grs, 256, 0, stream>>>(aw);

  k_init_acc<<<BHN, 256, 0, stream>>>(aw, initacc);

  k_scan<<<BHN, 64, 0, stream>>>(aw, initacc, evict);

  dim3 gpv(16, BHN);
  k_pv<<<gpv, 256, 0, stream>>>(aw, evict, (const ushort*)v, ao);

  dim3 gout(16, 32);
  k_pmm<<<gout, 256, 0, stream>>>(ao, Wo, bo, out, 1.0f, 0);
}